// Round 1
// baseline (13352.611 us; speedup 1.0000x reference)
//
#include <hip/hip_runtime.h>
#include <math.h>

#define NN 512
#define BB 32
#define UU 64
#define CC 128
#define TT 12
#define NP 12
#define RRR (NN*BB)   // 16384 rows = (n,b)

// ---- workspace layout (floats) ----
static const size_t OFF_ST   = 0;                              // [4][512][512]
static const size_t OFF_AH   = OFF_ST   + (size_t)4*512*512;   // [2][512][512]
static const size_t OFF_INVD = OFF_AH   + (size_t)2*512*512;   // [2][2][512]
static const size_t OFF_WSUM = OFF_INVD + 2048;                // 393216
static const size_t OFF_XH   = OFF_WSUM + 393216;              // [2][16384][128]
static const size_t OFF_H    = OFF_XH   + (size_t)2*RRR*CC;    // [2][16384][64]
static const size_t OFF_P    = OFF_H    + (size_t)2*RRR*UU;    // [4][16384][128]
static const size_t OFF_Q    = OFF_P    + (size_t)4*RRR*CC;    // [4][16384][64]
static const size_t OFF_RH   = OFF_Q    + (size_t)4*RRR*UU;    // [2][16384][64]
static const size_t OFF_U    = OFF_RH   + (size_t)2*RRR*UU;    // [2][16384][64]
static const size_t OFF_CB   = OFF_U    + (size_t)2*RRR*UU;    // [2][16384][64]

// ---------- precompute ----------
__global__ void k_build_ah(const float* __restrict__ adj, const float* __restrict__ sm1,
                           const float* __restrict__ sm2, float* __restrict__ ah) {
  int a = blockIdx.y, i = blockIdx.x;
  const float* sm = a ? sm2 : sm1;
  for (int j = threadIdx.x; j < NN; j += blockDim.x) {
    float m = tanhf(0.5f * (sm[i*NN + j] + sm[j*NN + i])) + 1.0f;
    ah[((size_t)a*NN + i)*NN + j] = adj[i*NN + j] * m + ((i == j) ? 1.0f : 0.0f);
  }
}

__global__ void k_deg(const float* __restrict__ ah, float* __restrict__ invd) {
  int a = blockIdx.y, n = blockIdx.x;
  const float* A = ah + (size_t)a*NN*NN;
  __shared__ float sr[256], sc[256];
  int t = threadIdx.x;
  sr[t] = A[(size_t)n*NN + t] + A[(size_t)n*NN + t + 256];
  sc[t] = A[(size_t)t*NN + n] + A[(size_t)(t+256)*NN + n];
  __syncthreads();
  for (int s = 128; s > 0; s >>= 1) {
    if (t < s) { sr[t] += sr[t+s]; sc[t] += sc[t+s]; }
    __syncthreads();
  }
  if (t == 0) {
    float dr = sr[0], dc = sc[0];
    invd[(a*2 + 0)*NN + n] = dr > 0.f ? 1.f/dr : 0.f;
    invd[(a*2 + 1)*NN + n] = dc > 0.f ? 1.f/dc : 0.f;
  }
}

// ST[s][m][n]: s=2a+0: inv_dout[a][n]*ah[a][n][m] ; s=2a+1: inv_din[a][n]*ah[a][m][n]
__global__ void k_st(const float* __restrict__ ah, const float* __restrict__ invd,
                     float* __restrict__ ST) {
  int s = blockIdx.y, m = blockIdx.x;
  int a = s >> 1, dir = s & 1;
  const float* A = ah + (size_t)a*NN*NN;
  const float* inv = invd + (a*2 + dir)*NN;
  float* out = ST + ((size_t)s*NN + m)*NN;
  for (int n = threadIdx.x; n < NN; n += blockDim.x) {
    float v = dir ? A[(size_t)m*NN + n] : A[(size_t)n*NN + m];
    out[n] = inv[n] * v;
  }
}

// w:[2][4][128][O] -> out:[2][2][128][O]  (fb=0: w0+w1, fb=1: w2+w3)
__global__ void k_wsum(const float* __restrict__ w, float* __restrict__ out, int O) {
  int idx = blockIdx.x*blockDim.x + threadIdx.x;
  int total = 2*2*128*O;
  if (idx >= total) return;
  int o  = idx % O;
  int i  = (idx / O) % 128;
  int fb = (idx / (O*128)) % 2;
  int l  = idx / (O*256);
  const float* wl = w + (((size_t)(l*4 + fb*2)*128 + i)*O + o);
  out[idx] = wl[0] + wl[(size_t)128*O];
}

// encoder step input: xh0[n][b][0:64] = (x[b,t,n]*(tanh(tm)+1))*fiw + fib
__global__ void k_xin(const float* __restrict__ x, const float* __restrict__ tm,
                      const float* __restrict__ fiw, const float* __restrict__ fib,
                      float* __restrict__ xh0, int t) {
  int idx = blockIdx.x*blockDim.x + threadIdx.x;  // 16384*64
  int u = idx & 63, R = idx >> 6;
  int b = R & 31, n = R >> 5;
  float xs = x[((size_t)b*TT + t)*NN + n] * (tanhf(tm[t*NN + n]) + 1.0f);
  xh0[(size_t)R*CC + u] = xs * fiw[u] + fib[u];
}

__global__ void k_decin0(const float* __restrict__ fiw, const float* __restrict__ fib,
                         float* __restrict__ xh0) {
  int idx = blockIdx.x*blockDim.x + threadIdx.x;
  int u = idx & 63, R = idx >> 6;
  (void)fiw;
  xh0[(size_t)R*CC + u] = fib[u];   // go == 0
}

// ---------- generic 128x128 fp32 tile GEMM: C = A@B ----------
__launch_bounds__(256)
__global__ void k_gemm(const float* __restrict__ Ag, int lda, long long aZ,
                       const float* __restrict__ Bg, int ldb, long long bZ,
                       float* __restrict__ Cg, int ldc, long long cZ, int K) {
  const float* A = Ag + (long long)blockIdx.z * aZ;
  const float* B = Bg + (long long)blockIdx.z * bZ;
  float* C = Cg + (long long)blockIdx.z * cZ;
  __shared__ __align__(16) float As[16][128];
  __shared__ __align__(16) float Bs[16][128];
  const int tid = threadIdx.x;
  const int ty = tid >> 4, tx = tid & 15;
  const int row0 = blockIdx.x * 128, col0 = blockIdx.y * 128;
  float acc[8][8];
#pragma unroll
  for (int i = 0; i < 8; ++i)
#pragma unroll
    for (int j = 0; j < 8; ++j) acc[i][j] = 0.f;

  for (int kt = 0; kt < K; kt += 16) {
#pragma unroll
    for (int i = 0; i < 2; ++i) {
      const int f = tid*2 + i;
      const int r = f >> 2, kc = (f & 3) << 2;
      const float4 va = *(const float4*)(A + (size_t)(row0 + r)*lda + kt + kc);
      As[kc+0][r] = va.x; As[kc+1][r] = va.y; As[kc+2][r] = va.z; As[kc+3][r] = va.w;
      const int kk = f >> 5, cc = (f & 31) << 2;
      *(float4*)(&Bs[kk][cc]) = *(const float4*)(B + (size_t)(kt + kk)*ldb + col0 + cc);
    }
    __syncthreads();
#pragma unroll
    for (int kk = 0; kk < 16; ++kk) {
      float a[8], b[8];
      *(float4*)(&a[0]) = *(const float4*)(&As[kk][ty*8]);
      *(float4*)(&a[4]) = *(const float4*)(&As[kk][ty*8 + 4]);
      *(float4*)(&b[0]) = *(const float4*)(&Bs[kk][tx*8]);
      *(float4*)(&b[4]) = *(const float4*)(&Bs[kk][tx*8 + 4]);
#pragma unroll
      for (int i = 0; i < 8; ++i)
#pragma unroll
        for (int j = 0; j < 8; ++j) acc[i][j] = fmaf(a[i], b[j], acc[i][j]);
    }
    __syncthreads();
  }
#pragma unroll
  for (int i = 0; i < 8; ++i) {
    const size_t off = (size_t)(row0 + ty*8 + i)*ldc + col0 + tx*8;
    *(float4*)(C + off)     = make_float4(acc[i][0], acc[i][1], acc[i][2], acc[i][3]);
    *(float4*)(C + off + 4) = make_float4(acc[i][4], acc[i][5], acc[i][6], acc[i][7]);
  }
}

// ---------- gates: ru = sigmoid(P[2g]@Wf + P[2g+1]@Wb + bias); rh=r*h, u stored ----------
__launch_bounds__(256)
__global__ void k_gates(const float* __restrict__ Pb, const float* __restrict__ Wg0,
                        const float* __restrict__ Wg1, const float* __restrict__ bg0,
                        const float* __restrict__ bg1, const float* __restrict__ h,
                        float* __restrict__ rh, float* __restrict__ ubuf) {
  const int g = blockIdx.z;
  const float* A1 = Pb + (size_t)(2*g)   * RRR * CC;
  const float* A2 = Pb + (size_t)(2*g+1) * RRR * CC;
  const float* W  = g ? Wg1 : Wg0;           // [2][128][128]
  const float* bias = g ? bg1 : bg0;
  float* rh_g = rh   + (size_t)g * RRR * UU;
  float* u_g  = ubuf + (size_t)g * RRR * UU;
  __shared__ __align__(16) float As1[16][128], As2[16][128], Ws1[16][128], Ws2[16][128];
  const int tid = threadIdx.x, ty = tid >> 4, tx = tid & 15;
  const int R0 = blockIdx.x * 128;
  float acc[8][8];
#pragma unroll
  for (int i = 0; i < 8; ++i)
#pragma unroll
    for (int j = 0; j < 8; ++j) acc[i][j] = 0.f;

  for (int kt = 0; kt < 128; kt += 16) {
#pragma unroll
    for (int i = 0; i < 2; ++i) {
      const int f = tid*2 + i;
      const int r = f >> 2, kc = (f & 3) << 2;
      float4 va = *(const float4*)(A1 + (size_t)(R0 + r)*CC + kt + kc);
      As1[kc+0][r]=va.x; As1[kc+1][r]=va.y; As1[kc+2][r]=va.z; As1[kc+3][r]=va.w;
      float4 vb = *(const float4*)(A2 + (size_t)(R0 + r)*CC + kt + kc);
      As2[kc+0][r]=vb.x; As2[kc+1][r]=vb.y; As2[kc+2][r]=vb.z; As2[kc+3][r]=vb.w;
      const int kk = f >> 5, cc = (f & 31) << 2;
      *(float4*)(&Ws1[kk][cc]) = *(const float4*)(W + (size_t)(kt+kk)*128 + cc);
      *(float4*)(&Ws2[kk][cc]) = *(const float4*)(W + (size_t)16384 + (size_t)(kt+kk)*128 + cc);
    }
    __syncthreads();
#pragma unroll
    for (int kk = 0; kk < 16; ++kk) {
      float a1[8], a2[8], w1[8], w2[8];
      *(float4*)(&a1[0]) = *(const float4*)(&As1[kk][ty*8]);
      *(float4*)(&a1[4]) = *(const float4*)(&As1[kk][ty*8+4]);
      *(float4*)(&a2[0]) = *(const float4*)(&As2[kk][ty*8]);
      *(float4*)(&a2[4]) = *(const float4*)(&As2[kk][ty*8+4]);
      *(float4*)(&w1[0]) = *(const float4*)(&Ws1[kk][tx*8]);
      *(float4*)(&w1[4]) = *(const float4*)(&Ws1[kk][tx*8+4]);
      *(float4*)(&w2[0]) = *(const float4*)(&Ws2[kk][tx*8]);
      *(float4*)(&w2[4]) = *(const float4*)(&Ws2[kk][tx*8+4]);
#pragma unroll
      for (int i = 0; i < 8; ++i)
#pragma unroll
        for (int j = 0; j < 8; ++j)
          acc[i][j] = fmaf(a1[i], w1[j], fmaf(a2[i], w2[j], acc[i][j]));
    }
    __syncthreads();
  }
#pragma unroll
  for (int i = 0; i < 8; ++i)
#pragma unroll
    for (int j = 0; j < 8; ++j) {
      const int R = R0 + ty*8 + i, o = tx*8 + j;
      float v = acc[i][j] + bias[o];
      float sg = 1.f / (1.f + expf(-v));
      if (o < 64) rh_g[(size_t)R*UU + o] = sg * h[(size_t)R*UU + o];
      else        u_g[(size_t)R*UU + o - 64] = sg;
    }
}

// ---------- candidate: c = tanh(Σ_seg A_seg@W_seg + bias) ----------
__launch_bounds__(256)
__global__ void k_cand(const float* __restrict__ Pb, const float* __restrict__ Qb,
                       const float* __restrict__ Wg0, const float* __restrict__ Wg1,
                       const float* __restrict__ bg0, const float* __restrict__ bg1,
                       float* __restrict__ cbuf) {
  const int g = blockIdx.z;
  const float* W = g ? Wg1 : Wg0;            // [2 fb][128][64]
  const float* bias = g ? bg1 : bg0;
  float* c_g = cbuf + (size_t)g * RRR * UU;
  __shared__ __align__(16) float As[16][128], Ws[16][64];
  const int tid = threadIdx.x, ty = tid >> 4, tx = tid & 15;
  const int R0 = blockIdx.x * 128;
  float acc[8][4];
#pragma unroll
  for (int i = 0; i < 8; ++i)
#pragma unroll
    for (int j = 0; j < 4; ++j) acc[i][j] = 0.f;

  for (int seg = 0; seg < 4; ++seg) {
    const int sup = 2*g + (seg >> 1);
    const int isQ = seg & 1;
    const float* A = isQ ? (Qb + (size_t)sup*RRR*UU) : (Pb + (size_t)sup*RRR*CC);
    const int lda = isQ ? UU : CC;
    const float* Wseg = W + (size_t)(seg >> 1)*(128*64) + (size_t)(isQ ? 64 : 0)*64;
    for (int kt = 0; kt < 64; kt += 16) {
#pragma unroll
      for (int i = 0; i < 2; ++i) {
        const int f = tid*2 + i;
        const int r = f >> 2, kc = (f & 3) << 2;
        float4 v = *(const float4*)(A + (size_t)(R0 + r)*lda + kt + kc);
        As[kc+0][r]=v.x; As[kc+1][r]=v.y; As[kc+2][r]=v.z; As[kc+3][r]=v.w;
      }
      {
        const int f = tid;
        const int kk = f >> 4, cc = (f & 15) << 2;
        *(float4*)(&Ws[kk][cc]) = *(const float4*)(Wseg + (size_t)(kt+kk)*64 + cc);
      }
      __syncthreads();
#pragma unroll
      for (int kk = 0; kk < 16; ++kk) {
        float a[8], w[4];
        *(float4*)(&a[0]) = *(const float4*)(&As[kk][ty*8]);
        *(float4*)(&a[4]) = *(const float4*)(&As[kk][ty*8+4]);
        *(float4*)(&w[0]) = *(const float4*)(&Ws[kk][tx*4]);
#pragma unroll
        for (int i = 0; i < 8; ++i)
#pragma unroll
          for (int j = 0; j < 4; ++j) acc[i][j] = fmaf(a[i], w[j], acc[i][j]);
      }
      __syncthreads();
    }
  }
#pragma unroll
  for (int i = 0; i < 8; ++i)
#pragma unroll
    for (int j = 0; j < 4; ++j) {
      const int R = R0 + ty*8 + i, o = tx*4 + j;
      c_g[(size_t)R*UU + o] = tanhf(acc[i][j] + bias[o]);
    }
}

// ---------- GRU update ----------
__global__ void k_update(const float* __restrict__ u1, const float* __restrict__ u2,
                         const float* __restrict__ c1, const float* __restrict__ c2,
                         float* __restrict__ h, float* __restrict__ xh,
                         float* __restrict__ xh_next) {
  int idx = blockIdx.x*blockDim.x + threadIdx.x;  // 16384*64
  int R = idx >> 6, o = idx & 63;
  float u = 0.5f*(u1[idx] + u2[idx]);
  float c = 0.5f*(c1[idx] + c2[idx]);
  float hn = (1.f - u)*h[idx] + u*c;
  h[idx] = hn;
  xh[(size_t)R*CC + 64 + o] = hn;
  if (xh_next) xh_next[(size_t)R*CC + o] = hn;
}

// ---------- decoder output + next input ----------
__global__ void k_out(const float* __restrict__ h1, const float* __restrict__ fow,
                      const float* __restrict__ fob, const float* __restrict__ fiw,
                      const float* __restrict__ fib, float* __restrict__ out,
                      float* __restrict__ xh0, int p) {
  int R = blockIdx.x*blockDim.x + threadIdx.x;   // 16384
  int b = R & 31, n = R >> 5;
  const float* hr = h1 + (size_t)R*UU;
  float s = fob[0];
#pragma unroll
  for (int u = 0; u < UU; ++u) s = fmaf(hr[u], fow[u], s);
  out[(size_t)b*(NP*NN) + (size_t)p*NN + n] = s;
#pragma unroll
  for (int u = 0; u < UU; ++u) xh0[(size_t)R*CC + u] = fmaf(s, fiw[u], fib[u]);
}

extern "C" void kernel_launch(void* const* d_in, const int* in_sizes, int n_in,
                              void* d_out, int out_size, void* d_ws, size_t ws_size,
                              hipStream_t stream) {
  (void)in_sizes; (void)n_in; (void)out_size; (void)ws_size;
  const float* x   = (const float*)d_in[0];
  const float* adj = (const float*)d_in[1];
  const float* sm1 = (const float*)d_in[2];
  const float* sm2 = (const float*)d_in[3];
  const float* tm  = (const float*)d_in[4];
  const float* fiw = (const float*)d_in[5];
  const float* fib = (const float*)d_in[6];
  const float* fow = (const float*)d_in[7];
  const float* fob = (const float*)d_in[8];

  float* WS   = (float*)d_ws;
  float* ST   = WS + OFF_ST;
  float* AH   = WS + OFF_AH;
  float* INVD = WS + OFF_INVD;
  float* WSUM = WS + OFF_WSUM;
  float* XH   = WS + OFF_XH;
  float* H    = WS + OFF_H;
  float* Pbuf = WS + OFF_P;
  float* Qbuf = WS + OFF_Q;
  float* RH   = WS + OFF_RH;
  float* Ubuf = WS + OFF_U;
  float* Cbuf = WS + OFF_CB;

  // ---- supports ----
  k_build_ah<<<dim3(512,2),256,0,stream>>>(adj, sm1, sm2, AH);
  k_deg<<<dim3(512,2),256,0,stream>>>(AH, INVD);
  k_st<<<dim3(512,4),256,0,stream>>>(AH, INVD, ST);

  // ---- weight sums: tensors in order enc_ru, enc_c, enc_ru2, enc_c2, dec_* ----
  const int widx[8] = {9, 11, 13, 15, 17, 19, 21, 23};
  const int Osz[8]  = {128, 64, 128, 64, 128, 64, 128, 64};
  const size_t woff[8] = {0, 65536, 98304, 163840, 196608, 262144, 294912, 360448};
  for (int tau = 0; tau < 8; ++tau) {
    int total = 2*2*128*Osz[tau];
    k_wsum<<<(total + 255)/256, 256, 0, stream>>>((const float*)d_in[widx[tau]],
                                                  WSUM + woff[tau], Osz[tau]);
  }

  hipMemsetAsync(XH, 0, (size_t)2*RRR*CC*sizeof(float), stream);
  hipMemsetAsync(H,  0, (size_t)2*RRR*UU*sizeof(float), stream);

  for (int step = 0; step < TT + NP; ++step) {
    const bool enc = step < TT;
    const int ph = enc ? 0 : 1;
    if (enc)            k_xin<<<4096,256,0,stream>>>(x, tm, fiw, fib, XH, step);
    else if (step == TT) k_decin0<<<4096,256,0,stream>>>(fiw, fib, XH);
    // later decoder steps: k_out of previous step already wrote XH x-part

    for (int l = 0; l < 2; ++l) {
      float* xh_l = XH + (size_t)l*RRR*CC;
      float* h_l  = H  + (size_t)l*RRR*UU;
      const float* Wru  = WSUM + woff[ph*4+0] + (size_t)l*2*128*128;
      const float* Wc   = WSUM + woff[ph*4+1] + (size_t)l*2*128*64;
      const float* Wru2 = WSUM + woff[ph*4+2] + (size_t)l*2*128*128;
      const float* Wc2  = WSUM + woff[ph*4+3] + (size_t)l*2*128*64;
      const float* bru  = (const float*)d_in[enc?10:18] + (size_t)l*128;
      const float* bc   = (const float*)d_in[enc?12:20] + (size_t)l*64;
      const float* bru2 = (const float*)d_in[enc?14:22] + (size_t)l*128;
      const float* bc2  = (const float*)d_in[enc?16:24] + (size_t)l*64;

      // K1: P[(s,m),(b,i)] = ST_all[2048,512] @ xh_l[512,4096]
      k_gemm<<<dim3(16,32,1),256,0,stream>>>(ST, 512, 0, xh_l, 4096, 0,
                                             Pbuf, 4096, 0, 512);
      // K2: gates (z = gate)
      k_gates<<<dim3(128,1,2),256,0,stream>>>(Pbuf, Wru, Wru2, bru, bru2, h_l, RH, Ubuf);
      // K3: Q = ST(pair g) @ rh_g   (z = gate)
      k_gemm<<<dim3(8,16,2),256,0,stream>>>(ST, 512, (long long)2*512*512,
                                            RH, 2048, (long long)RRR*UU,
                                            Qbuf, 2048, (long long)2*512*2048, 512);
      // K4: candidates (z = gate)
      k_cand<<<dim3(128,1,2),256,0,stream>>>(Pbuf, Qbuf, Wc, Wc2, bc, bc2, Cbuf);
      // K5: h update
      k_update<<<4096,256,0,stream>>>(Ubuf, Ubuf + (size_t)RRR*UU,
                                      Cbuf, Cbuf + (size_t)RRR*UU,
                                      h_l, xh_l, (l == 0) ? (XH + (size_t)RRR*CC) : nullptr);
    }
    if (!enc) {
      int p = step - TT;
      k_out<<<64,256,0,stream>>>(H + (size_t)RRR*UU, fow, fob, fiw, fib,
                                 (float*)d_out, XH, p);
    }
  }
}

// Round 2
// 8225.690 us; speedup vs baseline: 1.6233x; 1.6233x over previous
//
#include <hip/hip_runtime.h>
#include <math.h>

#define NN 512
#define BB 32
#define UU 64
#define CC 128
#define TT 12
#define NP 12
#define RRR (NN*BB)   // 16384 rows = (n,b)

typedef _Float16 f16;
typedef f16 f16x8 __attribute__((ext_vector_type(8)));
typedef f16 f16x4 __attribute__((ext_vector_type(4)));
typedef float f32x4 __attribute__((ext_vector_type(4)));

// ---- workspace layout (float units) ----
static const size_t OFF_ST   = 0;                              // [4][512][512]
static const size_t OFF_AH   = OFF_ST   + (size_t)4*512*512;   // [2][512][512]
static const size_t OFF_INVD = OFF_AH   + (size_t)2*512*512;   // [2][2][512]
static const size_t OFF_WSUM = OFF_INVD + 2048;                // 393216
static const size_t OFF_XH   = OFF_WSUM + 393216;              // [2][16384][128]
static const size_t OFF_H    = OFF_XH   + (size_t)2*RRR*CC;    // [2][16384][64]
static const size_t OFF_P    = OFF_H    + (size_t)2*RRR*UU;    // [4][16384][128]
static const size_t OFF_Q    = OFF_P    + (size_t)4*RRR*CC;    // [4][16384][64]
static const size_t OFF_RH   = OFF_Q    + (size_t)4*RRR*UU;    // [2][16384][64]
static const size_t OFF_U    = OFF_RH   + (size_t)2*RRR*UU;    // [2][16384][64]
static const size_t OFF_CB   = OFF_U    + (size_t)2*RRR*UU;    // [2][16384][64]
static const size_t OFF_END0 = OFF_CB   + (size_t)2*RRR*UU;
// f16 arrays (sizes below in float units = f16count/2)
static const size_t OFF_ST16A = OFF_END0;                 // 2048*512 f16
static const size_t OFF_ST16B = OFF_ST16A + 524288;       // 2048*512 f16
static const size_t OFF_XHT1  = OFF_ST16B + 524288;       // 4096*512 f16
static const size_t OFF_XHT2  = OFF_XHT1  + 1048576;
static const size_t OFF_RHT1  = OFF_XHT2  + 1048576;      // 2*2048*512 f16
static const size_t OFF_RHT2  = OFF_RHT1  + 1048576;

// ---------- precompute ----------
__global__ void k_build_ah(const float* __restrict__ adj, const float* __restrict__ sm1,
                           const float* __restrict__ sm2, float* __restrict__ ah) {
  int a = blockIdx.y, i = blockIdx.x;
  const float* sm = a ? sm2 : sm1;
  for (int j = threadIdx.x; j < NN; j += blockDim.x) {
    float m = tanhf(0.5f * (sm[i*NN + j] + sm[j*NN + i])) + 1.0f;
    ah[((size_t)a*NN + i)*NN + j] = adj[i*NN + j] * m + ((i == j) ? 1.0f : 0.0f);
  }
}

__global__ void k_deg(const float* __restrict__ ah, float* __restrict__ invd) {
  int a = blockIdx.y, n = blockIdx.x;
  const float* A = ah + (size_t)a*NN*NN;
  __shared__ float sr[256], sc[256];
  int t = threadIdx.x;
  sr[t] = A[(size_t)n*NN + t] + A[(size_t)n*NN + t + 256];
  sc[t] = A[(size_t)t*NN + n] + A[(size_t)(t+256)*NN + n];
  __syncthreads();
  for (int s = 128; s > 0; s >>= 1) {
    if (t < s) { sr[t] += sr[t+s]; sc[t] += sc[t+s]; }
    __syncthreads();
  }
  if (t == 0) {
    float dr = sr[0], dc = sc[0];
    invd[(a*2 + 0)*NN + n] = dr > 0.f ? 1.f/dr : 0.f;
    invd[(a*2 + 1)*NN + n] = dc > 0.f ? 1.f/dc : 0.f;
  }
}

// ST[s][m][n]: s=2a+0: inv_dout[a][n]*ah[a][n][m] ; s=2a+1: inv_din[a][n]*ah[a][m][n]
__global__ void k_st(const float* __restrict__ ah, const float* __restrict__ invd,
                     float* __restrict__ ST) {
  int s = blockIdx.y, m = blockIdx.x;
  int a = s >> 1, dir = s & 1;
  const float* A = ah + (size_t)a*NN*NN;
  const float* inv = invd + (a*2 + dir)*NN;
  float* out = ST + ((size_t)s*NN + m)*NN;
  for (int n = threadIdx.x; n < NN; n += blockDim.x) {
    float v = dir ? A[(size_t)m*NN + n] : A[(size_t)n*NN + m];
    out[n] = inv[n] * v;
  }
}

// fp16 split of ST with x256 scale
__global__ void k_splitA(const float* __restrict__ s, f16* __restrict__ a1,
                         f16* __restrict__ a2, int total) {
  int i = blockIdx.x*blockDim.x + threadIdx.x;
  if (i >= total) return;
  float v = s[i] * 256.0f;
  f16 hi = (f16)v;
  a1[i] = hi;
  a2[i] = (f16)(v - (float)hi);
}

// transpose + fp16-split: src f32 [512 x lds_] (rows k), dst f16 [ldsT? x 512] (rows col)
__launch_bounds__(256)
__global__ void k_tsplit(const float* __restrict__ src, int lds_, long long srcZ,
                         f16* __restrict__ d1, f16* __restrict__ d2, long long dstZ) {
  __shared__ float tile[64][65];
  const float* S = src + (size_t)blockIdx.z*srcZ;
  f16* D1 = d1 + (size_t)blockIdx.z*dstZ;
  f16* D2 = d2 + (size_t)blockIdx.z*dstZ;
  int t = threadIdx.x;
  int c0 = blockIdx.x*64, k0 = blockIdx.y*64;
#pragma unroll
  for (int it = 0; it < 4; ++it) {
    int r = (t >> 4) + it*16;
    int c = (t & 15)*4;
    float4 v = *(const float4*)(S + (size_t)(k0 + r)*lds_ + c0 + c);
    tile[r][c] = v.x; tile[r][c+1] = v.y; tile[r][c+2] = v.z; tile[r][c+3] = v.w;
  }
  __syncthreads();
#pragma unroll
  for (int it = 0; it < 4; ++it) {
    int c = (t >> 4) + it*16;       // dst row (source col)
    int ks = (t & 15)*4;
    f16x4 h1, h2;
#pragma unroll
    for (int j = 0; j < 4; ++j) {
      float v = tile[ks + j][c];
      f16 hi = (f16)v;
      h1[j] = hi;
      h2[j] = (f16)(v - (float)hi);
    }
    *(f16x4*)(D1 + (size_t)(c0 + c)*512 + k0 + ks) = h1;
    *(f16x4*)(D2 + (size_t)(c0 + c)*512 + k0 + ks) = h2;
  }
}

// ---------- fp16-split MFMA GEMM: C = (A1@B1 + A1@B2 + A2@B1)*scale ----------
// A* f16 [Mtot x 512] row-major (lda=512); B* f16 [Ntot x 512] = B^T (ldb=512); K=512.
__launch_bounds__(256)
__global__ void k_mm16(const f16* __restrict__ A1g, const f16* __restrict__ A2g, long long aZ,
                       const f16* __restrict__ B1g, const f16* __restrict__ B2g, long long bZ,
                       float* __restrict__ Cg, int ldc, long long cZ, float scale) {
  __shared__ __align__(16) f16 As[128*64];
  __shared__ __align__(16) f16 Bs[128*64];
  const int tid = threadIdx.x;
  const int lane = tid & 63, w = tid >> 6;
  const int wr = w >> 1, wc = w & 1;
  const long long z = blockIdx.z;
  const f16* A1 = A1g + z*aZ; const f16* A2 = A2g + z*aZ;
  const f16* B1 = B1g + z*bZ; const f16* B2 = B2g + z*bZ;
  float* C = Cg + z*cZ;
  const int row0 = blockIdx.x*128, col0 = blockIdx.y*128;

  f32x4 acc[4][4];
#pragma unroll
  for (int m = 0; m < 4; ++m)
#pragma unroll
    for (int n = 0; n < 4; ++n) acc[m][n] = (f32x4){0.f,0.f,0.f,0.f};

  for (int p = 0; p < 3; ++p) {
    const f16* Ap = (p < 2) ? A1 : A2;
    const f16* Bp = (p == 1) ? B2 : B1;
    for (int k0 = 0; k0 < 512; k0 += 64) {
      __syncthreads();
#pragma unroll
      for (int j = 0; j < 4; ++j) {
        int G = tid + 256*j;
        int r = G >> 3, g = G & 7;          // row (128), granule of 8 f16 (8)
        f16x8 va = *(const f16x8*)(Ap + (size_t)(row0 + r)*512 + k0 + g*8);
        *(f16x8*)(As + r*64 + ((g ^ (r & 7)) * 8)) = va;
        f16x8 vb = *(const f16x8*)(Bp + (size_t)(col0 + r)*512 + k0 + g*8);
        *(f16x8*)(Bs + r*64 + ((g ^ (r & 7)) * 8)) = vb;
      }
      __syncthreads();
#pragma unroll
      for (int ks = 0; ks < 2; ++ks) {
        f16x8 af[4], bf[4];
        const int gk = ks*4 + (lane >> 4);
#pragma unroll
        for (int m = 0; m < 4; ++m) {
          int ra = wr*64 + m*16 + (lane & 15);
          af[m] = *(const f16x8*)(As + ra*64 + ((gk ^ (ra & 7))*8));
          int rb = wc*64 + m*16 + (lane & 15);
          bf[m] = *(const f16x8*)(Bs + rb*64 + ((gk ^ (rb & 7))*8));
        }
#pragma unroll
        for (int m = 0; m < 4; ++m)
#pragma unroll
          for (int n = 0; n < 4; ++n)
            acc[m][n] = __builtin_amdgcn_mfma_f32_16x16x32_f16(af[m], bf[n], acc[m][n], 0, 0, 0);
      }
    }
  }
#pragma unroll
  for (int m = 0; m < 4; ++m) {
    const int row = row0 + wr*64 + m*16 + (lane >> 4)*4;
#pragma unroll
    for (int n = 0; n < 4; ++n) {
      const int col = col0 + wc*64 + n*16 + (lane & 15);
#pragma unroll
      for (int r = 0; r < 4; ++r)
        C[(size_t)(row + r)*ldc + col] = acc[m][n][r] * scale;
    }
  }
}

// w:[2][4][128][O] -> out:[2][2][128][O]  (fb=0: w0+w1, fb=1: w2+w3)
__global__ void k_wsum(const float* __restrict__ w, float* __restrict__ out, int O) {
  int idx = blockIdx.x*blockDim.x + threadIdx.x;
  int total = 2*2*128*O;
  if (idx >= total) return;
  int o  = idx % O;
  int i  = (idx / O) % 128;
  int fb = (idx / (O*128)) % 2;
  int l  = idx / (O*256);
  const float* wl = w + (((size_t)(l*4 + fb*2)*128 + i)*O + o);
  out[idx] = wl[0] + wl[(size_t)128*O];
}

__global__ void k_xin(const float* __restrict__ x, const float* __restrict__ tm,
                      const float* __restrict__ fiw, const float* __restrict__ fib,
                      float* __restrict__ xh0, int t) {
  int idx = blockIdx.x*blockDim.x + threadIdx.x;  // 16384*64
  int u = idx & 63, R = idx >> 6;
  int b = R & 31, n = R >> 5;
  float xs = x[((size_t)b*TT + t)*NN + n] * (tanhf(tm[t*NN + n]) + 1.0f);
  xh0[(size_t)R*CC + u] = xs * fiw[u] + fib[u];
}

__global__ void k_decin0(const float* __restrict__ fib, float* __restrict__ xh0) {
  int idx = blockIdx.x*blockDim.x + threadIdx.x;
  int u = idx & 63, R = idx >> 6;
  xh0[(size_t)R*CC + u] = fib[u];   // go == 0
}

// ---------- gates (fp32): ru = sigmoid(P[2g]@Wf + P[2g+1]@Wb + bias) ----------
__launch_bounds__(256)
__global__ void k_gates(const float* __restrict__ Pb, const float* __restrict__ Wg0,
                        const float* __restrict__ Wg1, const float* __restrict__ bg0,
                        const float* __restrict__ bg1, const float* __restrict__ h,
                        float* __restrict__ rh, float* __restrict__ ubuf) {
  const int g = blockIdx.z;
  const float* A1 = Pb + (size_t)(2*g)   * RRR * CC;
  const float* A2 = Pb + (size_t)(2*g+1) * RRR * CC;
  const float* W  = g ? Wg1 : Wg0;           // [2][128][128]
  const float* bias = g ? bg1 : bg0;
  float* rh_g = rh   + (size_t)g * RRR * UU;
  float* u_g  = ubuf + (size_t)g * RRR * UU;
  __shared__ __align__(16) float As1[16][128], As2[16][128], Ws1[16][128], Ws2[16][128];
  const int tid = threadIdx.x, ty = tid >> 4, tx = tid & 15;
  const int R0 = blockIdx.x * 128;
  float acc[8][8];
#pragma unroll
  for (int i = 0; i < 8; ++i)
#pragma unroll
    for (int j = 0; j < 8; ++j) acc[i][j] = 0.f;

  for (int kt = 0; kt < 128; kt += 16) {
#pragma unroll
    for (int i = 0; i < 2; ++i) {
      const int f = tid*2 + i;
      const int r = f >> 2, kc = (f & 3) << 2;
      float4 va = *(const float4*)(A1 + (size_t)(R0 + r)*CC + kt + kc);
      As1[kc+0][r]=va.x; As1[kc+1][r]=va.y; As1[kc+2][r]=va.z; As1[kc+3][r]=va.w;
      float4 vb = *(const float4*)(A2 + (size_t)(R0 + r)*CC + kt + kc);
      As2[kc+0][r]=vb.x; As2[kc+1][r]=vb.y; As2[kc+2][r]=vb.z; As2[kc+3][r]=vb.w;
      const int kk = f >> 5, cc = (f & 31) << 2;
      *(float4*)(&Ws1[kk][cc]) = *(const float4*)(W + (size_t)(kt+kk)*128 + cc);
      *(float4*)(&Ws2[kk][cc]) = *(const float4*)(W + (size_t)16384 + (size_t)(kt+kk)*128 + cc);
    }
    __syncthreads();
#pragma unroll
    for (int kk = 0; kk < 16; ++kk) {
      float a1[8], a2[8], w1[8], w2[8];
      *(float4*)(&a1[0]) = *(const float4*)(&As1[kk][ty*8]);
      *(float4*)(&a1[4]) = *(const float4*)(&As1[kk][ty*8+4]);
      *(float4*)(&a2[0]) = *(const float4*)(&As2[kk][ty*8]);
      *(float4*)(&a2[4]) = *(const float4*)(&As2[kk][ty*8+4]);
      *(float4*)(&w1[0]) = *(const float4*)(&Ws1[kk][tx*8]);
      *(float4*)(&w1[4]) = *(const float4*)(&Ws1[kk][tx*8+4]);
      *(float4*)(&w2[0]) = *(const float4*)(&Ws2[kk][tx*8]);
      *(float4*)(&w2[4]) = *(const float4*)(&Ws2[kk][tx*8+4]);
#pragma unroll
      for (int i = 0; i < 8; ++i)
#pragma unroll
        for (int j = 0; j < 8; ++j)
          acc[i][j] = fmaf(a1[i], w1[j], fmaf(a2[i], w2[j], acc[i][j]));
    }
    __syncthreads();
  }
#pragma unroll
  for (int i = 0; i < 8; ++i)
#pragma unroll
    for (int j = 0; j < 8; ++j) {
      const int R = R0 + ty*8 + i, o = tx*8 + j;
      float v = acc[i][j] + bias[o];
      float sg = 1.f / (1.f + expf(-v));
      if (o < 64) rh_g[(size_t)R*UU + o] = sg * h[(size_t)R*UU + o];
      else        u_g[(size_t)R*UU + o - 64] = sg;
    }
}

// ---------- candidate (fp32): c = tanh(Σ_seg A_seg@W_seg + bias) ----------
__launch_bounds__(256)
__global__ void k_cand(const float* __restrict__ Pb, const float* __restrict__ Qb,
                       const float* __restrict__ Wg0, const float* __restrict__ Wg1,
                       const float* __restrict__ bg0, const float* __restrict__ bg1,
                       float* __restrict__ cbuf) {
  const int g = blockIdx.z;
  const float* W = g ? Wg1 : Wg0;            // [2 fb][128][64]
  const float* bias = g ? bg1 : bg0;
  float* c_g = cbuf + (size_t)g * RRR * UU;
  __shared__ __align__(16) float As[16][128], Ws[16][64];
  const int tid = threadIdx.x, ty = tid >> 4, tx = tid & 15;
  const int R0 = blockIdx.x * 128;
  float acc[8][4];
#pragma unroll
  for (int i = 0; i < 8; ++i)
#pragma unroll
    for (int j = 0; j < 4; ++j) acc[i][j] = 0.f;

  for (int seg = 0; seg < 4; ++seg) {
    const int sup = 2*g + (seg >> 1);
    const int isQ = seg & 1;
    const float* A = isQ ? (Qb + (size_t)sup*RRR*UU) : (Pb + (size_t)sup*RRR*CC);
    const int lda = isQ ? UU : CC;
    const float* Wseg = W + (size_t)(seg >> 1)*(128*64) + (size_t)(isQ ? 64 : 0)*64;
    for (int kt = 0; kt < 64; kt += 16) {
#pragma unroll
      for (int i = 0; i < 2; ++i) {
        const int f = tid*2 + i;
        const int r = f >> 2, kc = (f & 3) << 2;
        float4 v = *(const float4*)(A + (size_t)(R0 + r)*lda + kt + kc);
        As[kc+0][r]=v.x; As[kc+1][r]=v.y; As[kc+2][r]=v.z; As[kc+3][r]=v.w;
      }
      {
        const int f = tid;
        const int kk = f >> 4, cc = (f & 15) << 2;
        *(float4*)(&Ws[kk][cc]) = *(const float4*)(Wseg + (size_t)(kt+kk)*64 + cc);
      }
      __syncthreads();
#pragma unroll
      for (int kk = 0; kk < 16; ++kk) {
        float a[8], wv[4];
        *(float4*)(&a[0]) = *(const float4*)(&As[kk][ty*8]);
        *(float4*)(&a[4]) = *(const float4*)(&As[kk][ty*8+4]);
        *(float4*)(&wv[0]) = *(const float4*)(&Ws[kk][tx*4]);
#pragma unroll
        for (int i = 0; i < 8; ++i)
#pragma unroll
          for (int j = 0; j < 4; ++j) acc[i][j] = fmaf(a[i], wv[j], acc[i][j]);
      }
      __syncthreads();
    }
  }
#pragma unroll
  for (int i = 0; i < 8; ++i)
#pragma unroll
    for (int j = 0; j < 4; ++j) {
      const int R = R0 + ty*8 + i, o = tx*4 + j;
      c_g[(size_t)R*UU + o] = tanhf(acc[i][j] + bias[o]);
    }
}

// ---------- GRU update ----------
__global__ void k_update(const float* __restrict__ u1, const float* __restrict__ u2,
                         const float* __restrict__ c1, const float* __restrict__ c2,
                         float* __restrict__ h, float* __restrict__ xh,
                         float* __restrict__ xh_next) {
  int idx = blockIdx.x*blockDim.x + threadIdx.x;  // 16384*64
  int R = idx >> 6, o = idx & 63;
  float u = 0.5f*(u1[idx] + u2[idx]);
  float c = 0.5f*(c1[idx] + c2[idx]);
  float hn = (1.f - u)*h[idx] + u*c;
  h[idx] = hn;
  xh[(size_t)R*CC + 64 + o] = hn;
  if (xh_next) xh_next[(size_t)R*CC + o] = hn;
}

// ---------- decoder output + next input ----------
__global__ void k_out(const float* __restrict__ h1, const float* __restrict__ fow,
                      const float* __restrict__ fob, const float* __restrict__ fiw,
                      const float* __restrict__ fib, float* __restrict__ out,
                      float* __restrict__ xh0, int p) {
  int R = blockIdx.x*blockDim.x + threadIdx.x;   // 16384
  int b = R & 31, n = R >> 5;
  const float* hr = h1 + (size_t)R*UU;
  float s = fob[0];
#pragma unroll
  for (int u = 0; u < UU; ++u) s = fmaf(hr[u], fow[u], s);
  out[(size_t)b*(NP*NN) + (size_t)p*NN + n] = s;
#pragma unroll
  for (int u = 0; u < UU; ++u) xh0[(size_t)R*CC + u] = fmaf(s, fiw[u], fib[u]);
}

extern "C" void kernel_launch(void* const* d_in, const int* in_sizes, int n_in,
                              void* d_out, int out_size, void* d_ws, size_t ws_size,
                              hipStream_t stream) {
  (void)in_sizes; (void)n_in; (void)out_size; (void)ws_size;
  const float* x   = (const float*)d_in[0];
  const float* adj = (const float*)d_in[1];
  const float* sm1 = (const float*)d_in[2];
  const float* sm2 = (const float*)d_in[3];
  const float* tm  = (const float*)d_in[4];
  const float* fiw = (const float*)d_in[5];
  const float* fib = (const float*)d_in[6];
  const float* fow = (const float*)d_in[7];
  const float* fob = (const float*)d_in[8];

  float* WS   = (float*)d_ws;
  float* ST   = WS + OFF_ST;
  float* AH   = WS + OFF_AH;
  float* INVD = WS + OFF_INVD;
  float* WSUM = WS + OFF_WSUM;
  float* XH   = WS + OFF_XH;
  float* H    = WS + OFF_H;
  float* Pbuf = WS + OFF_P;
  float* Qbuf = WS + OFF_Q;
  float* RH   = WS + OFF_RH;
  float* Ubuf = WS + OFF_U;
  float* Cbuf = WS + OFF_CB;
  f16* ST1  = (f16*)(WS + OFF_ST16A);
  f16* ST2  = (f16*)(WS + OFF_ST16B);
  f16* XHT1 = (f16*)(WS + OFF_XHT1);
  f16* XHT2 = (f16*)(WS + OFF_XHT2);
  f16* RHT1 = (f16*)(WS + OFF_RHT1);
  f16* RHT2 = (f16*)(WS + OFF_RHT2);

  // ---- supports ----
  k_build_ah<<<dim3(512,2),256,0,stream>>>(adj, sm1, sm2, AH);
  k_deg<<<dim3(512,2),256,0,stream>>>(AH, INVD);
  k_st<<<dim3(512,4),256,0,stream>>>(AH, INVD, ST);
  k_splitA<<<4096,256,0,stream>>>(ST, ST1, ST2, 2048*512);

  // ---- weight sums ----
  const int widx[8] = {9, 11, 13, 15, 17, 19, 21, 23};
  const int Osz[8]  = {128, 64, 128, 64, 128, 64, 128, 64};
  const size_t woff[8] = {0, 65536, 98304, 163840, 196608, 262144, 294912, 360448};
  for (int tau = 0; tau < 8; ++tau) {
    int total = 2*2*128*Osz[tau];
    k_wsum<<<(total + 255)/256, 256, 0, stream>>>((const float*)d_in[widx[tau]],
                                                  WSUM + woff[tau], Osz[tau]);
  }

  hipMemsetAsync(XH, 0, (size_t)2*RRR*CC*sizeof(float), stream);
  hipMemsetAsync(H,  0, (size_t)2*RRR*UU*sizeof(float), stream);

  const float inv256 = 1.0f/256.0f;

  for (int step = 0; step < TT + NP; ++step) {
    const bool enc = step < TT;
    const int ph = enc ? 0 : 1;
    if (enc)             k_xin<<<4096,256,0,stream>>>(x, tm, fiw, fib, XH, step);
    else if (step == TT) k_decin0<<<4096,256,0,stream>>>(fib, XH);

    for (int l = 0; l < 2; ++l) {
      float* xh_l = XH + (size_t)l*RRR*CC;
      float* h_l  = H  + (size_t)l*RRR*UU;
      const float* Wru  = WSUM + woff[ph*4+0] + (size_t)l*2*128*128;
      const float* Wc   = WSUM + woff[ph*4+1] + (size_t)l*2*128*64;
      const float* Wru2 = WSUM + woff[ph*4+2] + (size_t)l*2*128*128;
      const float* Wc2  = WSUM + woff[ph*4+3] + (size_t)l*2*128*64;
      const float* bru  = (const float*)d_in[enc?10:18] + (size_t)l*128;
      const float* bc   = (const float*)d_in[enc?12:20] + (size_t)l*64;
      const float* bru2 = (const float*)d_in[enc?14:22] + (size_t)l*128;
      const float* bc2  = (const float*)d_in[enc?16:24] + (size_t)l*64;

      // transpose+split xh_l: [512 x 4096] -> XHT [4096 x 512] f16 hi/lo
      k_tsplit<<<dim3(64,8,1),256,0,stream>>>(xh_l, 4096, 0, XHT1, XHT2, 0);
      // K1 (MFMA): P[2048 x 4096] = ST@xh
      k_mm16<<<dim3(16,32,1),256,0,stream>>>(ST1, ST2, 0, XHT1, XHT2, 0,
                                             Pbuf, 4096, 0, inv256);
      // K2: gates
      k_gates<<<dim3(128,1,2),256,0,stream>>>(Pbuf, Wru, Wru2, bru, bru2, h_l, RH, Ubuf);
      // transpose+split rh per gate: [512 x 2048] -> [2048 x 512]
      k_tsplit<<<dim3(32,8,2),256,0,stream>>>(RH, 2048, (long long)RRR*UU,
                                              RHT1, RHT2, (long long)2048*512);
      // K3 (MFMA): Q per gate: [1024 x 2048] = ST(pair g)@rh_g
      k_mm16<<<dim3(8,16,2),256,0,stream>>>(ST1, ST2, (long long)1024*512,
                                            RHT1, RHT2, (long long)2048*512,
                                            Qbuf, 2048, (long long)1024*2048, inv256);
      // K4: candidates
      k_cand<<<dim3(128,1,2),256,0,stream>>>(Pbuf, Qbuf, Wc, Wc2, bc, bc2, Cbuf);
      // K5: h update
      k_update<<<4096,256,0,stream>>>(Ubuf, Ubuf + (size_t)RRR*UU,
                                      Cbuf, Cbuf + (size_t)RRR*UU,
                                      h_l, xh_l, (l == 0) ? (XH + (size_t)RRR*CC) : nullptr);
    }
    if (!enc) {
      int p = step - TT;
      k_out<<<64,256,0,stream>>>(H + (size_t)RRR*UU, fow, fob, fiw, fib,
                                 (float*)d_out, XH, p);
    }
  }
}

// Round 3
// 6663.692 us; speedup vs baseline: 2.0038x; 1.2344x over previous
//
#include <hip/hip_runtime.h>
#include <math.h>

#define NN 512
#define BB 32
#define UU 64
#define CC 128
#define TT 12
#define NP 12
#define RRR (NN*BB)   // 16384 rows = (n,b)

typedef _Float16 f16;
typedef f16 f16x8 __attribute__((ext_vector_type(8)));
typedef f16 f16x4 __attribute__((ext_vector_type(4)));
typedef float f32x4 __attribute__((ext_vector_type(4)));

// ---- workspace layout (float units) ----
static const size_t OFF_ST    = 0;                              // [4][512][512] f32
static const size_t OFF_AH    = OFF_ST   + (size_t)4*512*512;
static const size_t OFF_INVD  = OFF_AH   + (size_t)2*512*512;
static const size_t OFF_XH    = OFF_INVD + 2048;                // [2][16384][128] f32
static const size_t OFF_H     = OFF_XH   + (size_t)2*RRR*CC;    // [2][16384][64] f32
static const size_t OFF_RH    = OFF_H    + (size_t)2*RRR*UU;    // [2][16384][64] f32
static const size_t OFF_U     = OFF_RH   + (size_t)2*RRR*UU;
static const size_t OFF_CB    = OFF_U    + (size_t)2*RRR*UU;
static const size_t OFF_F16   = OFF_CB   + (size_t)2*RRR*UU;
// f16 regions (float units = f16count/2)
static const size_t OFF_ST16A = OFF_F16;                        // 2048*512 f16
static const size_t OFF_ST16B = OFF_ST16A + 524288;
static const size_t OFF_XHT1  = OFF_ST16B + 524288;             // 4096*512 f16
static const size_t OFF_XHT2  = OFF_XHT1  + 1048576;
static const size_t OFF_RHT1  = OFF_XHT2  + 1048576;            // 2*2048*512 f16
static const size_t OFF_RHT2  = OFF_RHT1  + 1048576;
static const size_t OFF_P1    = OFF_RHT2  + 1048576;            // 2048*4096 f16
static const size_t OFF_P2    = OFF_P1    + 4194304;
static const size_t OFF_Q1    = OFF_P2    + 4194304;            // 4*512*2048 f16
static const size_t OFF_Q2    = OFF_Q1    + 2097152;
static const size_t OFF_WT1   = OFF_Q2    + 2097152;            // 393216 f16
static const size_t OFF_WT2   = OFF_WT1   + 196608;

// ---------- precompute ----------
__global__ void k_build_ah(const float* __restrict__ adj, const float* __restrict__ sm1,
                           const float* __restrict__ sm2, float* __restrict__ ah) {
  int a = blockIdx.y, i = blockIdx.x;
  const float* sm = a ? sm2 : sm1;
  for (int j = threadIdx.x; j < NN; j += blockDim.x) {
    float m = tanhf(0.5f * (sm[i*NN + j] + sm[j*NN + i])) + 1.0f;
    ah[((size_t)a*NN + i)*NN + j] = adj[i*NN + j] * m + ((i == j) ? 1.0f : 0.0f);
  }
}

__global__ void k_deg(const float* __restrict__ ah, float* __restrict__ invd) {
  int a = blockIdx.y, n = blockIdx.x;
  const float* A = ah + (size_t)a*NN*NN;
  __shared__ float sr[256], sc[256];
  int t = threadIdx.x;
  sr[t] = A[(size_t)n*NN + t] + A[(size_t)n*NN + t + 256];
  sc[t] = A[(size_t)t*NN + n] + A[(size_t)(t+256)*NN + n];
  __syncthreads();
  for (int s = 128; s > 0; s >>= 1) {
    if (t < s) { sr[t] += sr[t+s]; sc[t] += sc[t+s]; }
    __syncthreads();
  }
  if (t == 0) {
    float dr = sr[0], dc = sc[0];
    invd[(a*2 + 0)*NN + n] = dr > 0.f ? 1.f/dr : 0.f;
    invd[(a*2 + 1)*NN + n] = dc > 0.f ? 1.f/dc : 0.f;
  }
}

// ST[s][m][n]: s=2a+0: inv_dout[a][n]*ah[a][n][m] ; s=2a+1: inv_din[a][n]*ah[a][m][n]
__global__ void k_st(const float* __restrict__ ah, const float* __restrict__ invd,
                     float* __restrict__ ST) {
  int s = blockIdx.y, m = blockIdx.x;
  int a = s >> 1, dir = s & 1;
  const float* A = ah + (size_t)a*NN*NN;
  const float* inv = invd + (a*2 + dir)*NN;
  float* out = ST + ((size_t)s*NN + m)*NN;
  for (int n = threadIdx.x; n < NN; n += blockDim.x) {
    float v = dir ? A[(size_t)m*NN + n] : A[(size_t)n*NN + m];
    out[n] = inv[n] * v;
  }
}

// fp16 split of ST with x256 scale
__global__ void k_splitA(const float* __restrict__ s, f16* __restrict__ a1,
                         f16* __restrict__ a2, int total) {
  int i = blockIdx.x*blockDim.x + threadIdx.x;
  if (i >= total) return;
  float v = s[i] * 256.0f;
  f16 hi = (f16)v;
  a1[i] = hi;
  a2[i] = (f16)(v - (float)hi);
}

// weight transpose + sum + x256 split: w [2l][4][128][O] -> wt [2l][2fb][O][128]
__global__ void k_wsumt(const float* __restrict__ w, f16* __restrict__ wt1,
                        f16* __restrict__ wt2, int O) {
  int idx = blockIdx.x*blockDim.x + threadIdx.x;
  int total = 2*2*O*128;
  if (idx >= total) return;
  int i  = idx & 127;
  int o  = (idx >> 7) % O;
  int fb = (idx / (128*O)) & 1;
  int l  = idx / (128*O*2);
  const float* wl = w + (((size_t)(l*4 + fb*2)*128 + i)*O + o);
  float v = (wl[0] + wl[(size_t)128*O]) * 256.0f;
  f16 hi = (f16)v;
  size_t dst = ((size_t)(l*2 + fb)*O + o)*128 + i;
  wt1[dst] = hi;
  wt2[dst] = (f16)(v - (float)hi);
}

// transpose + fp16-split: src f32 [512 x lds_], dst f16 [cols x 512]
__launch_bounds__(256)
__global__ void k_tsplit(const float* __restrict__ src, int lds_, long long srcZ,
                         f16* __restrict__ d1, f16* __restrict__ d2, long long dstZ) {
  __shared__ float tile[64][65];
  const float* S = src + (size_t)blockIdx.z*srcZ;
  f16* D1 = d1 + (size_t)blockIdx.z*dstZ;
  f16* D2 = d2 + (size_t)blockIdx.z*dstZ;
  int t = threadIdx.x;
  int c0 = blockIdx.x*64, k0 = blockIdx.y*64;
#pragma unroll
  for (int it = 0; it < 4; ++it) {
    int r = (t >> 4) + it*16;
    int c = (t & 15)*4;
    float4 v = *(const float4*)(S + (size_t)(k0 + r)*lds_ + c0 + c);
    tile[r][c] = v.x; tile[r][c+1] = v.y; tile[r][c+2] = v.z; tile[r][c+3] = v.w;
  }
  __syncthreads();
#pragma unroll
  for (int it = 0; it < 4; ++it) {
    int c = (t >> 4) + it*16;       // dst row (source col)
    int ks = (t & 15)*4;
    f16x4 h1, h2;
#pragma unroll
    for (int j = 0; j < 4; ++j) {
      float v = tile[ks + j][c];
      f16 hi = (f16)v;
      h1[j] = hi;
      h2[j] = (f16)(v - (float)hi);
    }
    *(f16x4*)(D1 + (size_t)(c0 + c)*512 + k0 + ks) = h1;
    *(f16x4*)(D2 + (size_t)(c0 + c)*512 + k0 + ks) = h2;
  }
}

// ---------- fp16-split MFMA GEMM: C(split f16) = (A1B1 + A1B2 + A2B1)*scale ----------
// A* f16 [Mtot x 512] (lda=512); B* f16 [Ntot x 512] = B^T (ldb=512); K=512.
__launch_bounds__(256)
__global__ void k_mm16(const f16* __restrict__ A1g, const f16* __restrict__ A2g, long long aZ,
                       const f16* __restrict__ B1g, const f16* __restrict__ B2g, long long bZ,
                       f16* __restrict__ C1g, f16* __restrict__ C2g, int ldc, long long cZ,
                       float scale) {
  __shared__ __align__(16) f16 As[128*64];
  __shared__ __align__(16) f16 Bs[128*64];
  const int tid = threadIdx.x;
  const int lane = tid & 63, w = tid >> 6;
  const int wr = w >> 1, wc = w & 1;
  const long long z = blockIdx.z;
  const f16* A1 = A1g + z*aZ; const f16* A2 = A2g + z*aZ;
  const f16* B1 = B1g + z*bZ; const f16* B2 = B2g + z*bZ;
  f16* C1 = C1g + z*cZ; f16* C2 = C2g + z*cZ;
  const int row0 = blockIdx.x*128, col0 = blockIdx.y*128;

  f32x4 acc[4][4];
#pragma unroll
  for (int m = 0; m < 4; ++m)
#pragma unroll
    for (int n = 0; n < 4; ++n) acc[m][n] = (f32x4){0.f,0.f,0.f,0.f};

  for (int p = 0; p < 3; ++p) {
    const f16* Ap = (p < 2) ? A1 : A2;
    const f16* Bp = (p == 1) ? B2 : B1;
    for (int k0 = 0; k0 < 512; k0 += 64) {
      __syncthreads();
#pragma unroll
      for (int j = 0; j < 4; ++j) {
        int G = tid + 256*j;
        int r = G >> 3, g = G & 7;
        f16x8 va = *(const f16x8*)(Ap + (size_t)(row0 + r)*512 + k0 + g*8);
        *(f16x8*)(As + r*64 + ((g ^ (r & 7)) * 8)) = va;
        f16x8 vb = *(const f16x8*)(Bp + (size_t)(col0 + r)*512 + k0 + g*8);
        *(f16x8*)(Bs + r*64 + ((g ^ (r & 7)) * 8)) = vb;
      }
      __syncthreads();
#pragma unroll
      for (int ks = 0; ks < 2; ++ks) {
        f16x8 af[4], bf[4];
        const int gk = ks*4 + (lane >> 4);
#pragma unroll
        for (int m = 0; m < 4; ++m) {
          int ra = wr*64 + m*16 + (lane & 15);
          af[m] = *(const f16x8*)(As + ra*64 + ((gk ^ (ra & 7))*8));
          int rb = wc*64 + m*16 + (lane & 15);
          bf[m] = *(const f16x8*)(Bs + rb*64 + ((gk ^ (rb & 7))*8));
        }
#pragma unroll
        for (int m = 0; m < 4; ++m)
#pragma unroll
          for (int n = 0; n < 4; ++n)
            acc[m][n] = __builtin_amdgcn_mfma_f32_16x16x32_f16(af[m], bf[n], acc[m][n], 0, 0, 0);
      }
    }
  }
#pragma unroll
  for (int m = 0; m < 4; ++m) {
    const int row = row0 + wr*64 + m*16 + (lane >> 4)*4;
#pragma unroll
    for (int n = 0; n < 4; ++n) {
      const int col = col0 + wc*64 + n*16 + (lane & 15);
#pragma unroll
      for (int r = 0; r < 4; ++r) {
        float v = acc[m][n][r] * scale;
        f16 hi = (f16)v;
        C1[(size_t)(row + r)*ldc + col] = hi;
        C2[(size_t)(row + r)*ldc + col] = (f16)(v - (float)hi);
      }
    }
  }
}

// ---------- gates MFMA: G = sum_sup P[2g+sup] @ WT[fb=sup]^T ; sigmoid epilogue ----------
__launch_bounds__(256)
__global__ void k_gatesm(const f16* __restrict__ P1, const f16* __restrict__ P2,
                         const f16* __restrict__ W1g0, const f16* __restrict__ W2g0,
                         const f16* __restrict__ W1g1, const f16* __restrict__ W2g1,
                         const float* __restrict__ b0, const float* __restrict__ b1,
                         const float* __restrict__ h,
                         float* __restrict__ rh, float* __restrict__ ubuf) {
  const int g = blockIdx.z;
  const f16* W1 = g ? W1g1 : W1g0;
  const f16* W2 = g ? W2g1 : W2g0;
  const float* bias = g ? b1 : b0;
  float* rh_g = rh   + (size_t)g * RRR * UU;
  float* u_g  = ubuf + (size_t)g * RRR * UU;
  __shared__ __align__(16) f16 As[128*64];
  __shared__ __align__(16) f16 Bs[128*64];
  const int tid = threadIdx.x;
  const int lane = tid & 63, w = tid >> 6;
  const int wr = w >> 1, wc = w & 1;
  const int R0 = blockIdx.x * 128;

  f32x4 acc[4][4];
#pragma unroll
  for (int m = 0; m < 4; ++m)
#pragma unroll
    for (int n = 0; n < 4; ++n) acc[m][n] = (f32x4){0.f,0.f,0.f,0.f};

  for (int sup = 0; sup < 2; ++sup) {
    const f16* A1 = P1 + (size_t)(2*g + sup)*RRR*CC;
    const f16* A2 = P2 + (size_t)(2*g + sup)*RRR*CC;
    const f16* B1 = W1 + (size_t)sup*16384;
    const f16* B2 = W2 + (size_t)sup*16384;
    for (int p = 0; p < 3; ++p) {
      const f16* Ap = (p < 2) ? A1 : A2;
      const f16* Bp = (p == 1) ? B2 : B1;
      for (int k0 = 0; k0 < 128; k0 += 64) {
        __syncthreads();
#pragma unroll
        for (int j = 0; j < 4; ++j) {
          int G = tid + 256*j;
          int r = G >> 3, gg = G & 7;
          f16x8 va = *(const f16x8*)(Ap + (size_t)(R0 + r)*128 + k0 + gg*8);
          *(f16x8*)(As + r*64 + ((gg ^ (r & 7)) * 8)) = va;
          f16x8 vb = *(const f16x8*)(Bp + (size_t)r*128 + k0 + gg*8);
          *(f16x8*)(Bs + r*64 + ((gg ^ (r & 7)) * 8)) = vb;
        }
        __syncthreads();
#pragma unroll
        for (int ks = 0; ks < 2; ++ks) {
          f16x8 af[4], bf[4];
          const int gk = ks*4 + (lane >> 4);
#pragma unroll
          for (int m = 0; m < 4; ++m) {
            int ra = wr*64 + m*16 + (lane & 15);
            af[m] = *(const f16x8*)(As + ra*64 + ((gk ^ (ra & 7))*8));
            int rb = wc*64 + m*16 + (lane & 15);
            bf[m] = *(const f16x8*)(Bs + rb*64 + ((gk ^ (rb & 7))*8));
          }
#pragma unroll
          for (int m = 0; m < 4; ++m)
#pragma unroll
            for (int n = 0; n < 4; ++n)
              acc[m][n] = __builtin_amdgcn_mfma_f32_16x16x32_f16(af[m], bf[n], acc[m][n], 0, 0, 0);
        }
      }
    }
  }
#pragma unroll
  for (int m = 0; m < 4; ++m) {
    const int row = R0 + wr*64 + m*16 + (lane >> 4)*4;
#pragma unroll
    for (int n = 0; n < 4; ++n) {
      const int o = wc*64 + n*16 + (lane & 15);
#pragma unroll
      for (int r = 0; r < 4; ++r) {
        const int R = row + r;
        float v = acc[m][n][r] * 0.00390625f + bias[o];
        float sg = 1.f / (1.f + expf(-v));
        if (o < 64) rh_g[(size_t)R*UU + o] = sg * h[(size_t)R*UU + o];
        else        u_g[(size_t)R*UU + o - 64] = sg;
      }
    }
  }
}

// ---------- candidate MFMA: c = tanh(sum_seg A_seg @ W_seg^T + bias) ----------
__launch_bounds__(256)
__global__ void k_candm(const f16* __restrict__ P1, const f16* __restrict__ P2,
                        const f16* __restrict__ Q1, const f16* __restrict__ Q2,
                        const f16* __restrict__ Wc1g0, const f16* __restrict__ Wc2g0,
                        const f16* __restrict__ Wc1g1, const f16* __restrict__ Wc2g1,
                        const float* __restrict__ b0, const float* __restrict__ b1,
                        float* __restrict__ cbuf) {
  const int g = blockIdx.z;
  const f16* W1 = g ? Wc1g1 : Wc1g0;
  const f16* W2 = g ? Wc2g1 : Wc2g0;
  const float* bias = g ? b1 : b0;
  float* c_g = cbuf + (size_t)g * RRR * UU;
  __shared__ __align__(16) f16 As[256*64];
  __shared__ __align__(16) f16 Bs[64*64];
  const int tid = threadIdx.x;
  const int lane = tid & 63, w = tid >> 6;   // w = wave row block (0..3)
  const int R0 = blockIdx.x * 256;

  f32x4 acc[4][4];
#pragma unroll
  for (int m = 0; m < 4; ++m)
#pragma unroll
    for (int n = 0; n < 4; ++n) acc[m][n] = (f32x4){0.f,0.f,0.f,0.f};

  for (int seg = 0; seg < 4; ++seg) {
    const int sup = seg >> 1, isQ = seg & 1;
    const f16* A1 = isQ ? (Q1 + ((size_t)g*2 + sup)*1048576)
                        : (P1 + (size_t)(2*g + sup)*RRR*CC);
    const f16* A2 = isQ ? (Q2 + ((size_t)g*2 + sup)*1048576)
                        : (P2 + (size_t)(2*g + sup)*RRR*CC);
    const int lda = isQ ? 64 : 128;
    const f16* B1 = W1 + (size_t)sup*8192 + (isQ ? 64 : 0);
    const f16* B2 = W2 + (size_t)sup*8192 + (isQ ? 64 : 0);
    for (int p = 0; p < 3; ++p) {
      const f16* Ap = (p < 2) ? A1 : A2;
      const f16* Bp = (p == 1) ? B2 : B1;
      __syncthreads();
#pragma unroll
      for (int j = 0; j < 8; ++j) {
        int G = tid + 256*j;
        int r = G >> 3, gg = G & 7;
        f16x8 va = *(const f16x8*)(Ap + (size_t)(R0 + r)*lda + gg*8);
        *(f16x8*)(As + r*64 + ((gg ^ (r & 7)) * 8)) = va;
      }
#pragma unroll
      for (int j = 0; j < 2; ++j) {
        int G = tid + 256*j;
        int r = G >> 3, gg = G & 7;
        f16x8 vb = *(const f16x8*)(Bp + (size_t)r*128 + gg*8);
        *(f16x8*)(Bs + r*64 + ((gg ^ (r & 7)) * 8)) = vb;
      }
      __syncthreads();
#pragma unroll
      for (int ks = 0; ks < 2; ++ks) {
        f16x8 af[4], bf[4];
        const int gk = ks*4 + (lane >> 4);
#pragma unroll
        for (int m = 0; m < 4; ++m) {
          int ra = w*64 + m*16 + (lane & 15);
          af[m] = *(const f16x8*)(As + ra*64 + ((gk ^ (ra & 7))*8));
          int rb = m*16 + (lane & 15);      // n-index reuse: cols 0..63
          bf[m] = *(const f16x8*)(Bs + rb*64 + ((gk ^ (rb & 7))*8));
        }
#pragma unroll
        for (int m = 0; m < 4; ++m)
#pragma unroll
          for (int n = 0; n < 4; ++n)
            acc[m][n] = __builtin_amdgcn_mfma_f32_16x16x32_f16(af[m], bf[n], acc[m][n], 0, 0, 0);
      }
    }
  }
#pragma unroll
  for (int m = 0; m < 4; ++m) {
    const int row = R0 + w*64 + m*16 + (lane >> 4)*4;
#pragma unroll
    for (int n = 0; n < 4; ++n) {
      const int o = n*16 + (lane & 15);
#pragma unroll
      for (int r = 0; r < 4; ++r)
        c_g[(size_t)(row + r)*UU + o] = tanhf(acc[m][n][r] * 0.00390625f + bias[o]);
    }
  }
}

__global__ void k_xin(const float* __restrict__ x, const float* __restrict__ tm,
                      const float* __restrict__ fiw, const float* __restrict__ fib,
                      float* __restrict__ xh0, int t) {
  int idx = blockIdx.x*blockDim.x + threadIdx.x;  // 16384*64
  int u = idx & 63, R = idx >> 6;
  int b = R & 31, n = R >> 5;
  float xs = x[((size_t)b*TT + t)*NN + n] * (tanhf(tm[t*NN + n]) + 1.0f);
  xh0[(size_t)R*CC + u] = xs * fiw[u] + fib[u];
}

__global__ void k_decin0(const float* __restrict__ fib, float* __restrict__ xh0) {
  int idx = blockIdx.x*blockDim.x + threadIdx.x;
  int u = idx & 63, R = idx >> 6;
  xh0[(size_t)R*CC + u] = fib[u];   // go == 0
}

// ---------- GRU update ----------
__global__ void k_update(const float* __restrict__ u1, const float* __restrict__ u2,
                         const float* __restrict__ c1, const float* __restrict__ c2,
                         float* __restrict__ h, float* __restrict__ xh,
                         float* __restrict__ xh_next) {
  int idx = blockIdx.x*blockDim.x + threadIdx.x;  // 16384*64
  int R = idx >> 6, o = idx & 63;
  float u = 0.5f*(u1[idx] + u2[idx]);
  float c = 0.5f*(c1[idx] + c2[idx]);
  float hn = (1.f - u)*h[idx] + u*c;
  h[idx] = hn;
  xh[(size_t)R*CC + 64 + o] = hn;
  if (xh_next) xh_next[(size_t)R*CC + o] = hn;
}

// ---------- decoder output + next input ----------
__global__ void k_out(const float* __restrict__ h1, const float* __restrict__ fow,
                      const float* __restrict__ fob, const float* __restrict__ fiw,
                      const float* __restrict__ fib, float* __restrict__ out,
                      float* __restrict__ xh0, int p) {
  int R = blockIdx.x*blockDim.x + threadIdx.x;   // 16384
  int b = R & 31, n = R >> 5;
  const float* hr = h1 + (size_t)R*UU;
  float s = fob[0];
#pragma unroll
  for (int u = 0; u < UU; ++u) s = fmaf(hr[u], fow[u], s);
  out[(size_t)b*(NP*NN) + (size_t)p*NN + n] = s;
#pragma unroll
  for (int u = 0; u < UU; ++u) xh0[(size_t)R*CC + u] = fmaf(s, fiw[u], fib[u]);
}

extern "C" void kernel_launch(void* const* d_in, const int* in_sizes, int n_in,
                              void* d_out, int out_size, void* d_ws, size_t ws_size,
                              hipStream_t stream) {
  (void)in_sizes; (void)n_in; (void)out_size; (void)ws_size;
  const float* x   = (const float*)d_in[0];
  const float* adj = (const float*)d_in[1];
  const float* sm1 = (const float*)d_in[2];
  const float* sm2 = (const float*)d_in[3];
  const float* tm  = (const float*)d_in[4];
  const float* fiw = (const float*)d_in[5];
  const float* fib = (const float*)d_in[6];
  const float* fow = (const float*)d_in[7];
  const float* fob = (const float*)d_in[8];

  float* WS   = (float*)d_ws;
  float* ST   = WS + OFF_ST;
  float* AH   = WS + OFF_AH;
  float* INVD = WS + OFF_INVD;
  float* XH   = WS + OFF_XH;
  float* H    = WS + OFF_H;
  float* RH   = WS + OFF_RH;
  float* Ubuf = WS + OFF_U;
  float* Cbuf = WS + OFF_CB;
  f16* ST1  = (f16*)(WS + OFF_ST16A);
  f16* ST2  = (f16*)(WS + OFF_ST16B);
  f16* XHT1 = (f16*)(WS + OFF_XHT1);
  f16* XHT2 = (f16*)(WS + OFF_XHT2);
  f16* RHT1 = (f16*)(WS + OFF_RHT1);
  f16* RHT2 = (f16*)(WS + OFF_RHT2);
  f16* P1   = (f16*)(WS + OFF_P1);
  f16* P2   = (f16*)(WS + OFF_P2);
  f16* Q1   = (f16*)(WS + OFF_Q1);
  f16* Q2   = (f16*)(WS + OFF_Q2);
  f16* WT1  = (f16*)(WS + OFF_WT1);
  f16* WT2  = (f16*)(WS + OFF_WT2);

  // ---- supports ----
  k_build_ah<<<dim3(512,2),256,0,stream>>>(adj, sm1, sm2, AH);
  k_deg<<<dim3(512,2),256,0,stream>>>(AH, INVD);
  k_st<<<dim3(512,4),256,0,stream>>>(AH, INVD, ST);
  k_splitA<<<4096,256,0,stream>>>(ST, ST1, ST2, 2048*512);

  // ---- weight transposed split sums ----
  const int widx[8] = {9, 11, 13, 15, 17, 19, 21, 23};
  const int Osz[8]  = {128, 64, 128, 64, 128, 64, 128, 64};
  const size_t woff16[8] = {0, 65536, 98304, 163840, 196608, 262144, 294912, 360448};
  for (int tau = 0; tau < 8; ++tau) {
    int total = 2*2*Osz[tau]*128;
    k_wsumt<<<(total + 255)/256, 256, 0, stream>>>((const float*)d_in[widx[tau]],
                                                   WT1 + woff16[tau], WT2 + woff16[tau],
                                                   Osz[tau]);
  }

  hipMemsetAsync(XH, 0, (size_t)2*RRR*CC*sizeof(float), stream);
  hipMemsetAsync(H,  0, (size_t)2*RRR*UU*sizeof(float), stream);

  const float inv256 = 1.0f/256.0f;

  for (int step = 0; step < TT + NP; ++step) {
    const bool enc = step < TT;
    const int ph = enc ? 0 : 1;
    if (enc)             k_xin<<<4096,256,0,stream>>>(x, tm, fiw, fib, XH, step);
    else if (step == TT) k_decin0<<<4096,256,0,stream>>>(fib, XH);

    for (int l = 0; l < 2; ++l) {
      float* xh_l = XH + (size_t)l*RRR*CC;
      float* h_l  = H  + (size_t)l*RRR*UU;
      const size_t lru = (size_t)l*2*128*128;  // layer stride in WT for O=128
      const size_t lc  = (size_t)l*2*64*128;   // layer stride for O=64
      const f16* Wru1a = WT1 + woff16[ph*4+0] + lru;  // gate0 ru
      const f16* Wru2a = WT2 + woff16[ph*4+0] + lru;
      const f16* Wru1b = WT1 + woff16[ph*4+2] + lru;  // gate1 ru2
      const f16* Wru2b = WT2 + woff16[ph*4+2] + lru;
      const f16* Wc1a  = WT1 + woff16[ph*4+1] + lc;   // gate0 c
      const f16* Wc2a  = WT2 + woff16[ph*4+1] + lc;
      const f16* Wc1b  = WT1 + woff16[ph*4+3] + lc;   // gate1 c2
      const f16* Wc2b  = WT2 + woff16[ph*4+3] + lc;
      const float* bru  = (const float*)d_in[enc?10:18] + (size_t)l*128;
      const float* bc   = (const float*)d_in[enc?12:20] + (size_t)l*64;
      const float* bru2 = (const float*)d_in[enc?14:22] + (size_t)l*128;
      const float* bc2  = (const float*)d_in[enc?16:24] + (size_t)l*64;

      // transpose+split xh_l: [512 x 4096] -> XHT [4096 x 512] f16 hi/lo
      k_tsplit<<<dim3(64,8,1),256,0,stream>>>(xh_l, 4096, 0, XHT1, XHT2, 0);
      // K1 (MFMA): P[2048 x 4096] = ST@xh  (split f16 out)
      k_mm16<<<dim3(16,32,1),256,0,stream>>>(ST1, ST2, 0, XHT1, XHT2, 0,
                                             P1, P2, 4096, 0, inv256);
      // K2 (MFMA): gates -> rh, u
      k_gatesm<<<dim3(128,1,2),256,0,stream>>>(P1, P2, Wru1a, Wru2a, Wru1b, Wru2b,
                                               bru, bru2, h_l, RH, Ubuf);
      // transpose+split rh per gate: [512 x 2048] -> [2048 x 512]
      k_tsplit<<<dim3(32,8,2),256,0,stream>>>(RH, 2048, (long long)RRR*UU,
                                              RHT1, RHT2, (long long)2048*512);
      // K3 (MFMA): Q per gate: [1024 x 2048] = ST(pair g)@rh_g (split f16 out)
      k_mm16<<<dim3(8,16,2),256,0,stream>>>(ST1, ST2, (long long)1024*512,
                                            RHT1, RHT2, (long long)2048*512,
                                            Q1, Q2, 2048, (long long)1024*2048, inv256);
      // K4 (MFMA): candidates
      k_candm<<<dim3(64,1,2),256,0,stream>>>(P1, P2, Q1, Q2, Wc1a, Wc2a, Wc1b, Wc2b,
                                             bc, bc2, Cbuf);
      // K5: h update
      k_update<<<4096,256,0,stream>>>(Ubuf, Ubuf + (size_t)RRR*UU,
                                      Cbuf, Cbuf + (size_t)RRR*UU,
                                      h_l, xh_l, (l == 0) ? (XH + (size_t)RRR*CC) : nullptr);
    }
    if (!enc) {
      int p = step - TT;
      k_out<<<64,256,0,stream>>>(H + (size_t)RRR*UU, fow, fob, fiw, fib,
                                 (float*)d_out, XH, p);
    }
  }
}

// Round 4
// 6573.879 us; speedup vs baseline: 2.0312x; 1.0137x over previous
//
#include <hip/hip_runtime.h>
#include <math.h>

#define NN 512
#define BB 32
#define UU 64
#define CC 128
#define TT 12
#define NP 12
#define RRR (NN*BB)   // 16384 rows = (n,b)

typedef _Float16 f16;
typedef f16 f16x8 __attribute__((ext_vector_type(8)));
typedef f16 f16x4 __attribute__((ext_vector_type(4)));
typedef float f32x4 __attribute__((ext_vector_type(4)));

// direct global->LDS DMA, 16B per lane; dst must be wave-uniform base (lane*16 added by HW)
__device__ __forceinline__ void gload16(const f16* g, f16* l) {
  __builtin_amdgcn_global_load_lds((const __attribute__((address_space(1))) void*)g,
                                   (__attribute__((address_space(3))) void*)l, 16, 0, 0);
}

// ---- workspace layout (float units) ----
static const size_t OFF_ST    = 0;                              // [4][512][512] f32
static const size_t OFF_AH    = OFF_ST   + (size_t)4*512*512;
static const size_t OFF_INVD  = OFF_AH   + (size_t)2*512*512;
static const size_t OFF_XH    = OFF_INVD + 2048;                // [2][16384][128] f32
static const size_t OFF_H     = OFF_XH   + (size_t)2*RRR*CC;    // [2][16384][64] f32
static const size_t OFF_RH    = OFF_H    + (size_t)2*RRR*UU;    // [2][16384][64] f32
static const size_t OFF_U     = OFF_RH   + (size_t)2*RRR*UU;
static const size_t OFF_CB    = OFF_U    + (size_t)2*RRR*UU;
static const size_t OFF_F16   = OFF_CB   + (size_t)2*RRR*UU;
// f16 regions (float units = f16count/2)
static const size_t OFF_ST16A = OFF_F16;                        // 2048*512 f16
static const size_t OFF_ST16B = OFF_ST16A + 524288;
static const size_t OFF_XHT1  = OFF_ST16B + 524288;             // 4096*512 f16
static const size_t OFF_XHT2  = OFF_XHT1  + 1048576;
static const size_t OFF_RHT1  = OFF_XHT2  + 1048576;            // 2*2048*512 f16
static const size_t OFF_RHT2  = OFF_RHT1  + 1048576;
static const size_t OFF_P1    = OFF_RHT2  + 1048576;            // 2048*4096 f16
static const size_t OFF_P2    = OFF_P1    + 4194304;
static const size_t OFF_Q1    = OFF_P2    + 4194304;            // 4*512*2048 f16
static const size_t OFF_Q2    = OFF_Q1    + 2097152;
static const size_t OFF_WT1   = OFF_Q2    + 2097152;            // 393216 f16
static const size_t OFF_WT2   = OFF_WT1   + 196608;

// ---------- precompute ----------
__global__ void k_build_ah(const float* __restrict__ adj, const float* __restrict__ sm1,
                           const float* __restrict__ sm2, float* __restrict__ ah) {
  int a = blockIdx.y, i = blockIdx.x;
  const float* sm = a ? sm2 : sm1;
  for (int j = threadIdx.x; j < NN; j += blockDim.x) {
    float m = tanhf(0.5f * (sm[i*NN + j] + sm[j*NN + i])) + 1.0f;
    ah[((size_t)a*NN + i)*NN + j] = adj[i*NN + j] * m + ((i == j) ? 1.0f : 0.0f);
  }
}

__global__ void k_deg(const float* __restrict__ ah, float* __restrict__ invd) {
  int a = blockIdx.y, n = blockIdx.x;
  const float* A = ah + (size_t)a*NN*NN;
  __shared__ float sr[256], sc[256];
  int t = threadIdx.x;
  sr[t] = A[(size_t)n*NN + t] + A[(size_t)n*NN + t + 256];
  sc[t] = A[(size_t)t*NN + n] + A[(size_t)(t+256)*NN + n];
  __syncthreads();
  for (int s = 128; s > 0; s >>= 1) {
    if (t < s) { sr[t] += sr[t+s]; sc[t] += sc[t+s]; }
    __syncthreads();
  }
  if (t == 0) {
    float dr = sr[0], dc = sc[0];
    invd[(a*2 + 0)*NN + n] = dr > 0.f ? 1.f/dr : 0.f;
    invd[(a*2 + 1)*NN + n] = dc > 0.f ? 1.f/dc : 0.f;
  }
}

// ST[s][m][n]: s=2a+0: inv_dout[a][n]*ah[a][n][m] ; s=2a+1: inv_din[a][n]*ah[a][m][n]
__global__ void k_st(const float* __restrict__ ah, const float* __restrict__ invd,
                     float* __restrict__ ST) {
  int s = blockIdx.y, m = blockIdx.x;
  int a = s >> 1, dir = s & 1;
  const float* A = ah + (size_t)a*NN*NN;
  const float* inv = invd + (a*2 + dir)*NN;
  float* out = ST + ((size_t)s*NN + m)*NN;
  for (int n = threadIdx.x; n < NN; n += blockDim.x) {
    float v = dir ? A[(size_t)m*NN + n] : A[(size_t)n*NN + m];
    out[n] = inv[n] * v;
  }
}

// fp16 split of ST with x256 scale
__global__ void k_splitA(const float* __restrict__ s, f16* __restrict__ a1,
                         f16* __restrict__ a2, int total) {
  int i = blockIdx.x*blockDim.x + threadIdx.x;
  if (i >= total) return;
  float v = s[i] * 256.0f;
  f16 hi = (f16)v;
  a1[i] = hi;
  a2[i] = (f16)(v - (float)hi);
}

// weight transpose + sum + x256 split: w [2l][4][128][O] -> wt [2l][2fb][O][128]
__global__ void k_wsumt(const float* __restrict__ w, f16* __restrict__ wt1,
                        f16* __restrict__ wt2, int O) {
  int idx = blockIdx.x*blockDim.x + threadIdx.x;
  int total = 2*2*O*128;
  if (idx >= total) return;
  int i  = idx & 127;
  int o  = (idx >> 7) % O;
  int fb = (idx / (128*O)) & 1;
  int l  = idx / (128*O*2);
  const float* wl = w + (((size_t)(l*4 + fb*2)*128 + i)*O + o);
  float v = (wl[0] + wl[(size_t)128*O]) * 256.0f;
  f16 hi = (f16)v;
  size_t dst = ((size_t)(l*2 + fb)*O + o)*128 + i;
  wt1[dst] = hi;
  wt2[dst] = (f16)(v - (float)hi);
}

// transpose + fp16-split: src f32 [512 x lds_], dst f16 [cols x 512]
__launch_bounds__(256)
__global__ void k_tsplit(const float* __restrict__ src, int lds_, long long srcZ,
                         f16* __restrict__ d1, f16* __restrict__ d2, long long dstZ) {
  __shared__ float tile[64][65];
  const float* S = src + (size_t)blockIdx.z*srcZ;
  f16* D1 = d1 + (size_t)blockIdx.z*dstZ;
  f16* D2 = d2 + (size_t)blockIdx.z*dstZ;
  int t = threadIdx.x;
  int c0 = blockIdx.x*64, k0 = blockIdx.y*64;
#pragma unroll
  for (int it = 0; it < 4; ++it) {
    int r = (t >> 4) + it*16;
    int c = (t & 15)*4;
    float4 v = *(const float4*)(S + (size_t)(k0 + r)*lds_ + c0 + c);
    tile[r][c] = v.x; tile[r][c+1] = v.y; tile[r][c+2] = v.z; tile[r][c+3] = v.w;
  }
  __syncthreads();
#pragma unroll
  for (int it = 0; it < 4; ++it) {
    int c = (t >> 4) + it*16;       // dst row (source col)
    int ks = (t & 15)*4;
    f16x4 h1, h2;
#pragma unroll
    for (int j = 0; j < 4; ++j) {
      float v = tile[ks + j][c];
      f16 hi = (f16)v;
      h1[j] = hi;
      h2[j] = (f16)(v - (float)hi);
    }
    *(f16x4*)(D1 + (size_t)(c0 + c)*512 + k0 + ks) = h1;
    *(f16x4*)(D2 + (size_t)(c0 + c)*512 + k0 + ks) = h2;
  }
}

// ---------- fp16-split MFMA GEMM: C(split f16) = (A1B1 + A1B2 + A2B1)*scale ----------
// A* f16 [Mtot x 512] (lda=512); B* f16 [Ntot x 512] = B^T (ldb=512); K=512.
// Staging via global_load_lds with pre-swizzled global source (linear LDS dest).
__launch_bounds__(256)
__global__ void k_mm16(const f16* __restrict__ A1g, const f16* __restrict__ A2g, long long aZ,
                       const f16* __restrict__ B1g, const f16* __restrict__ B2g, long long bZ,
                       f16* __restrict__ C1g, f16* __restrict__ C2g, int ldc, long long cZ,
                       float scale) {
  __shared__ __align__(16) f16 As[128*64];
  __shared__ __align__(16) f16 Bs[128*64];
  const int tid = threadIdx.x;
  const int lane = tid & 63, w = tid >> 6;
  const int wr = w >> 1, wc = w & 1;
  const long long z = blockIdx.z;
  const f16* A1 = A1g + z*aZ; const f16* A2 = A2g + z*aZ;
  const f16* B1 = B1g + z*bZ; const f16* B2 = B2g + z*bZ;
  f16* C1 = C1g + z*cZ; f16* C2 = C2g + z*cZ;
  const int row0 = blockIdx.x*128, col0 = blockIdx.y*128;

  // staging lane geometry: lane i covers row (base+ (i>>3)), swizzled granule (i&7)^((i>>3)&7)
  const int rq = lane >> 3;
  const int gq = ((lane & 7) ^ rq) * 8;   // f16 elements

  f32x4 acc[4][4];
#pragma unroll
  for (int m = 0; m < 4; ++m)
#pragma unroll
    for (int n = 0; n < 4; ++n) acc[m][n] = (f32x4){0.f,0.f,0.f,0.f};

  for (int p = 0; p < 3; ++p) {
    const f16* Ap = (p < 2) ? A1 : A2;
    const f16* Bp = (p == 1) ? B2 : B1;
    for (int k0 = 0; k0 < 512; k0 += 64) {
      __syncthreads();
#pragma unroll
      for (int q = 0; q < 4; ++q) {
        const int rloc = w*32 + q*8;      // wave-uniform row base (multiple of 8)
        gload16(Ap + (size_t)(row0 + rloc + rq)*512 + k0 + gq, As + rloc*64);
        gload16(Bp + (size_t)(col0 + rloc + rq)*512 + k0 + gq, Bs + rloc*64);
      }
      __syncthreads();
#pragma unroll
      for (int ks = 0; ks < 2; ++ks) {
        f16x8 af[4], bf[4];
        const int gk = ks*4 + (lane >> 4);
#pragma unroll
        for (int m = 0; m < 4; ++m) {
          int ra = wr*64 + m*16 + (lane & 15);
          af[m] = *(const f16x8*)(As + ra*64 + ((gk ^ (ra & 7))*8));
          int rb = wc*64 + m*16 + (lane & 15);
          bf[m] = *(const f16x8*)(Bs + rb*64 + ((gk ^ (rb & 7))*8));
        }
#pragma unroll
        for (int m = 0; m < 4; ++m)
#pragma unroll
          for (int n = 0; n < 4; ++n)
            acc[m][n] = __builtin_amdgcn_mfma_f32_16x16x32_f16(af[m], bf[n], acc[m][n], 0, 0, 0);
      }
    }
  }
#pragma unroll
  for (int m = 0; m < 4; ++m) {
    const int row = row0 + wr*64 + m*16 + (lane >> 4)*4;
#pragma unroll
    for (int n = 0; n < 4; ++n) {
      const int col = col0 + wc*64 + n*16 + (lane & 15);
#pragma unroll
      for (int r = 0; r < 4; ++r) {
        float v = acc[m][n][r] * scale;
        f16 hi = (f16)v;
        C1[(size_t)(row + r)*ldc + col] = hi;
        C2[(size_t)(row + r)*ldc + col] = (f16)(v - (float)hi);
      }
    }
  }
}

// ---------- gates MFMA: G = sum_sup P[2g+sup] @ WT[fb=sup]^T ; sigmoid epilogue ----------
__launch_bounds__(256)
__global__ void k_gatesm(const f16* __restrict__ P1, const f16* __restrict__ P2,
                         const f16* __restrict__ W1g0, const f16* __restrict__ W2g0,
                         const f16* __restrict__ W1g1, const f16* __restrict__ W2g1,
                         const float* __restrict__ b0, const float* __restrict__ b1,
                         const float* __restrict__ h,
                         float* __restrict__ rh, float* __restrict__ ubuf) {
  const int g = blockIdx.z;
  const f16* W1 = g ? W1g1 : W1g0;
  const f16* W2 = g ? W2g1 : W2g0;
  const float* bias = g ? b1 : b0;
  float* rh_g = rh   + (size_t)g * RRR * UU;
  float* u_g  = ubuf + (size_t)g * RRR * UU;
  __shared__ __align__(16) f16 As[128*64];
  __shared__ __align__(16) f16 Bs[128*64];
  const int tid = threadIdx.x;
  const int lane = tid & 63, w = tid >> 6;
  const int wr = w >> 1, wc = w & 1;
  const int R0 = blockIdx.x * 128;

  const int rq = lane >> 3;
  const int gq = ((lane & 7) ^ rq) * 8;

  f32x4 acc[4][4];
#pragma unroll
  for (int m = 0; m < 4; ++m)
#pragma unroll
    for (int n = 0; n < 4; ++n) acc[m][n] = (f32x4){0.f,0.f,0.f,0.f};

  for (int sup = 0; sup < 2; ++sup) {
    const f16* A1 = P1 + (size_t)(2*g + sup)*RRR*CC;
    const f16* A2 = P2 + (size_t)(2*g + sup)*RRR*CC;
    const f16* B1 = W1 + (size_t)sup*16384;
    const f16* B2 = W2 + (size_t)sup*16384;
    for (int p = 0; p < 3; ++p) {
      const f16* Ap = (p < 2) ? A1 : A2;
      const f16* Bp = (p == 1) ? B2 : B1;
      for (int k0 = 0; k0 < 128; k0 += 64) {
        __syncthreads();
#pragma unroll
        for (int q = 0; q < 4; ++q) {
          const int rloc = w*32 + q*8;
          gload16(Ap + (size_t)(R0 + rloc + rq)*128 + k0 + gq, As + rloc*64);
          gload16(Bp + (size_t)(rloc + rq)*128 + k0 + gq, Bs + rloc*64);
        }
        __syncthreads();
#pragma unroll
        for (int ks = 0; ks < 2; ++ks) {
          f16x8 af[4], bf[4];
          const int gk = ks*4 + (lane >> 4);
#pragma unroll
          for (int m = 0; m < 4; ++m) {
            int ra = wr*64 + m*16 + (lane & 15);
            af[m] = *(const f16x8*)(As + ra*64 + ((gk ^ (ra & 7))*8));
            int rb = wc*64 + m*16 + (lane & 15);
            bf[m] = *(const f16x8*)(Bs + rb*64 + ((gk ^ (rb & 7))*8));
          }
#pragma unroll
          for (int m = 0; m < 4; ++m)
#pragma unroll
            for (int n = 0; n < 4; ++n)
              acc[m][n] = __builtin_amdgcn_mfma_f32_16x16x32_f16(af[m], bf[n], acc[m][n], 0, 0, 0);
        }
      }
    }
  }
#pragma unroll
  for (int m = 0; m < 4; ++m) {
    const int row = R0 + wr*64 + m*16 + (lane >> 4)*4;
#pragma unroll
    for (int n = 0; n < 4; ++n) {
      const int o = wc*64 + n*16 + (lane & 15);
#pragma unroll
      for (int r = 0; r < 4; ++r) {
        const int R = row + r;
        float v = acc[m][n][r] * 0.00390625f + bias[o];
        float sg = 1.f / (1.f + expf(-v));
        if (o < 64) rh_g[(size_t)R*UU + o] = sg * h[(size_t)R*UU + o];
        else        u_g[(size_t)R*UU + o - 64] = sg;
      }
    }
  }
}

// ---------- candidate MFMA: c = tanh(sum_seg A_seg @ W_seg^T + bias) ----------
__launch_bounds__(256)
__global__ void k_candm(const f16* __restrict__ P1, const f16* __restrict__ P2,
                        const f16* __restrict__ Q1, const f16* __restrict__ Q2,
                        const f16* __restrict__ Wc1g0, const f16* __restrict__ Wc2g0,
                        const f16* __restrict__ Wc1g1, const f16* __restrict__ Wc2g1,
                        const float* __restrict__ b0, const float* __restrict__ b1,
                        float* __restrict__ cbuf) {
  const int g = blockIdx.z;
  const f16* W1 = g ? Wc1g1 : Wc1g0;
  const f16* W2 = g ? Wc2g1 : Wc2g0;
  const float* bias = g ? b1 : b0;
  float* c_g = cbuf + (size_t)g * RRR * UU;
  __shared__ __align__(16) f16 As[256*64];
  __shared__ __align__(16) f16 Bs[64*64];
  const int tid = threadIdx.x;
  const int lane = tid & 63, w = tid >> 6;   // w = wave row block (0..3)
  const int R0 = blockIdx.x * 256;

  f32x4 acc[4][4];
#pragma unroll
  for (int m = 0; m < 4; ++m)
#pragma unroll
    for (int n = 0; n < 4; ++n) acc[m][n] = (f32x4){0.f,0.f,0.f,0.f};

  for (int seg = 0; seg < 4; ++seg) {
    const int sup = seg >> 1, isQ = seg & 1;
    const f16* A1 = isQ ? (Q1 + ((size_t)g*2 + sup)*1048576)
                        : (P1 + (size_t)(2*g + sup)*RRR*CC);
    const f16* A2 = isQ ? (Q2 + ((size_t)g*2 + sup)*1048576)
                        : (P2 + (size_t)(2*g + sup)*RRR*CC);
    const int lda = isQ ? 64 : 128;
    const f16* B1 = W1 + (size_t)sup*8192 + (isQ ? 64 : 0);
    const f16* B2 = W2 + (size_t)sup*8192 + (isQ ? 64 : 0);
    for (int p = 0; p < 3; ++p) {
      const f16* Ap = (p < 2) ? A1 : A2;
      const f16* Bp = (p == 1) ? B2 : B1;
      __syncthreads();
#pragma unroll
      for (int j = 0; j < 8; ++j) {
        int G = tid + 256*j;
        int r = G >> 3, gg = G & 7;
        f16x8 va = *(const f16x8*)(Ap + (size_t)(R0 + r)*lda + gg*8);
        *(f16x8*)(As + r*64 + ((gg ^ (r & 7)) * 8)) = va;
      }
#pragma unroll
      for (int j = 0; j < 2; ++j) {
        int G = tid + 256*j;
        int r = G >> 3, gg = G & 7;
        f16x8 vb = *(const f16x8*)(Bp + (size_t)r*128 + gg*8);
        *(f16x8*)(Bs + r*64 + ((gg ^ (r & 7)) * 8)) = vb;
      }
      __syncthreads();
#pragma unroll
      for (int ks = 0; ks < 2; ++ks) {
        f16x8 af[4], bf[4];
        const int gk = ks*4 + (lane >> 4);
#pragma unroll
        for (int m = 0; m < 4; ++m) {
          int ra = w*64 + m*16 + (lane & 15);
          af[m] = *(const f16x8*)(As + ra*64 + ((gk ^ (ra & 7))*8));
          int rb = m*16 + (lane & 15);      // n-index reuse: cols 0..63
          bf[m] = *(const f16x8*)(Bs + rb*64 + ((gk ^ (rb & 7))*8));
        }
#pragma unroll
        for (int m = 0; m < 4; ++m)
#pragma unroll
          for (int n = 0; n < 4; ++n)
            acc[m][n] = __builtin_amdgcn_mfma_f32_16x16x32_f16(af[m], bf[n], acc[m][n], 0, 0, 0);
      }
    }
  }
#pragma unroll
  for (int m = 0; m < 4; ++m) {
    const int row = R0 + w*64 + m*16 + (lane >> 4)*4;
#pragma unroll
    for (int n = 0; n < 4; ++n) {
      const int o = n*16 + (lane & 15);
#pragma unroll
      for (int r = 0; r < 4; ++r)
        c_g[(size_t)(row + r)*UU + o] = tanhf(acc[m][n][r] * 0.00390625f + bias[o]);
    }
  }
}

__global__ void k_xin(const float* __restrict__ x, const float* __restrict__ tm,
                      const float* __restrict__ fiw, const float* __restrict__ fib,
                      float* __restrict__ xh0, int t) {
  int idx = blockIdx.x*blockDim.x + threadIdx.x;  // 16384*64
  int u = idx & 63, R = idx >> 6;
  int b = R & 31, n = R >> 5;
  float xs = x[((size_t)b*TT + t)*NN + n] * (tanhf(tm[t*NN + n]) + 1.0f);
  xh0[(size_t)R*CC + u] = xs * fiw[u] + fib[u];
}

__global__ void k_decin0(const float* __restrict__ fib, float* __restrict__ xh0) {
  int idx = blockIdx.x*blockDim.x + threadIdx.x;
  int u = idx & 63, R = idx >> 6;
  xh0[(size_t)R*CC + u] = fib[u];   // go == 0
}

// ---------- GRU update ----------
__global__ void k_update(const float* __restrict__ u1, const float* __restrict__ u2,
                         const float* __restrict__ c1, const float* __restrict__ c2,
                         float* __restrict__ h, float* __restrict__ xh,
                         float* __restrict__ xh_next) {
  int idx = blockIdx.x*blockDim.x + threadIdx.x;  // 16384*64
  int R = idx >> 6, o = idx & 63;
  float u = 0.5f*(u1[idx] + u2[idx]);
  float c = 0.5f*(c1[idx] + c2[idx]);
  float hn = (1.f - u)*h[idx] + u*c;
  h[idx] = hn;
  xh[(size_t)R*CC + 64 + o] = hn;
  if (xh_next) xh_next[(size_t)R*CC + o] = hn;
}

// ---------- decoder output + next input ----------
__global__ void k_out(const float* __restrict__ h1, const float* __restrict__ fow,
                      const float* __restrict__ fob, const float* __restrict__ fiw,
                      const float* __restrict__ fib, float* __restrict__ out,
                      float* __restrict__ xh0, int p) {
  int R = blockIdx.x*blockDim.x + threadIdx.x;   // 16384
  int b = R & 31, n = R >> 5;
  const float* hr = h1 + (size_t)R*UU;
  float s = fob[0];
#pragma unroll
  for (int u = 0; u < UU; ++u) s = fmaf(hr[u], fow[u], s);
  out[(size_t)b*(NP*NN) + (size_t)p*NN + n] = s;
#pragma unroll
  for (int u = 0; u < UU; ++u) xh0[(size_t)R*CC + u] = fmaf(s, fiw[u], fib[u]);
}

extern "C" void kernel_launch(void* const* d_in, const int* in_sizes, int n_in,
                              void* d_out, int out_size, void* d_ws, size_t ws_size,
                              hipStream_t stream) {
  (void)in_sizes; (void)n_in; (void)out_size; (void)ws_size;
  const float* x   = (const float*)d_in[0];
  const float* adj = (const float*)d_in[1];
  const float* sm1 = (const float*)d_in[2];
  const float* sm2 = (const float*)d_in[3];
  const float* tm  = (const float*)d_in[4];
  const float* fiw = (const float*)d_in[5];
  const float* fib = (const float*)d_in[6];
  const float* fow = (const float*)d_in[7];
  const float* fob = (const float*)d_in[8];

  float* WS   = (float*)d_ws;
  float* ST   = WS + OFF_ST;
  float* AH   = WS + OFF_AH;
  float* INVD = WS + OFF_INVD;
  float* XH   = WS + OFF_XH;
  float* H    = WS + OFF_H;
  float* RH   = WS + OFF_RH;
  float* Ubuf = WS + OFF_U;
  float* Cbuf = WS + OFF_CB;
  f16* ST1  = (f16*)(WS + OFF_ST16A);
  f16* ST2  = (f16*)(WS + OFF_ST16B);
  f16* XHT1 = (f16*)(WS + OFF_XHT1);
  f16* XHT2 = (f16*)(WS + OFF_XHT2);
  f16* RHT1 = (f16*)(WS + OFF_RHT1);
  f16* RHT2 = (f16*)(WS + OFF_RHT2);
  f16* P1   = (f16*)(WS + OFF_P1);
  f16* P2   = (f16*)(WS + OFF_P2);
  f16* Q1   = (f16*)(WS + OFF_Q1);
  f16* Q2   = (f16*)(WS + OFF_Q2);
  f16* WT1  = (f16*)(WS + OFF_WT1);
  f16* WT2  = (f16*)(WS + OFF_WT2);

  // ---- supports ----
  k_build_ah<<<dim3(512,2),256,0,stream>>>(adj, sm1, sm2, AH);
  k_deg<<<dim3(512,2),256,0,stream>>>(AH, INVD);
  k_st<<<dim3(512,4),256,0,stream>>>(AH, INVD, ST);
  k_splitA<<<4096,256,0,stream>>>(ST, ST1, ST2, 2048*512);

  // ---- weight transposed split sums ----
  const int widx[8] = {9, 11, 13, 15, 17, 19, 21, 23};
  const int Osz[8]  = {128, 64, 128, 64, 128, 64, 128, 64};
  const size_t woff16[8] = {0, 65536, 98304, 163840, 196608, 262144, 294912, 360448};
  for (int tau = 0; tau < 8; ++tau) {
    int total = 2*2*Osz[tau]*128;
    k_wsumt<<<(total + 255)/256, 256, 0, stream>>>((const float*)d_in[widx[tau]],
                                                   WT1 + woff16[tau], WT2 + woff16[tau],
                                                   Osz[tau]);
  }

  hipMemsetAsync(XH, 0, (size_t)2*RRR*CC*sizeof(float), stream);
  hipMemsetAsync(H,  0, (size_t)2*RRR*UU*sizeof(float), stream);

  const float inv256 = 1.0f/256.0f;

  for (int step = 0; step < TT + NP; ++step) {
    const bool enc = step < TT;
    const int ph = enc ? 0 : 1;
    if (enc)             k_xin<<<4096,256,0,stream>>>(x, tm, fiw, fib, XH, step);
    else if (step == TT) k_decin0<<<4096,256,0,stream>>>(fib, XH);

    for (int l = 0; l < 2; ++l) {
      float* xh_l = XH + (size_t)l*RRR*CC;
      float* h_l  = H  + (size_t)l*RRR*UU;
      const size_t lru = (size_t)l*2*128*128;  // layer stride in WT for O=128
      const size_t lc  = (size_t)l*2*64*128;   // layer stride for O=64
      const f16* Wru1a = WT1 + woff16[ph*4+0] + lru;  // gate0 ru
      const f16* Wru2a = WT2 + woff16[ph*4+0] + lru;
      const f16* Wru1b = WT1 + woff16[ph*4+2] + lru;  // gate1 ru2
      const f16* Wru2b = WT2 + woff16[ph*4+2] + lru;
      const f16* Wc1a  = WT1 + woff16[ph*4+1] + lc;   // gate0 c
      const f16* Wc2a  = WT2 + woff16[ph*4+1] + lc;
      const f16* Wc1b  = WT1 + woff16[ph*4+3] + lc;   // gate1 c2
      const f16* Wc2b  = WT2 + woff16[ph*4+3] + lc;
      const float* bru  = (const float*)d_in[enc?10:18] + (size_t)l*128;
      const float* bc   = (const float*)d_in[enc?12:20] + (size_t)l*64;
      const float* bru2 = (const float*)d_in[enc?14:22] + (size_t)l*128;
      const float* bc2  = (const float*)d_in[enc?16:24] + (size_t)l*64;

      // transpose+split xh_l: [512 x 4096] -> XHT [4096 x 512] f16 hi/lo
      k_tsplit<<<dim3(64,8,1),256,0,stream>>>(xh_l, 4096, 0, XHT1, XHT2, 0);
      // K1 (MFMA): P[2048 x 4096] = ST@xh  (split f16 out)
      k_mm16<<<dim3(16,32,1),256,0,stream>>>(ST1, ST2, 0, XHT1, XHT2, 0,
                                             P1, P2, 4096, 0, inv256);
      // K2 (MFMA): gates -> rh, u
      k_gatesm<<<dim3(128,1,2),256,0,stream>>>(P1, P2, Wru1a, Wru2a, Wru1b, Wru2b,
                                               bru, bru2, h_l, RH, Ubuf);
      // transpose+split rh per gate: [512 x 2048] -> [2048 x 512]
      k_tsplit<<<dim3(32,8,2),256,0,stream>>>(RH, 2048, (long long)RRR*UU,
                                              RHT1, RHT2, (long long)2048*512);
      // K3 (MFMA): Q per gate: [1024 x 2048] = ST(pair g)@rh_g (split f16 out)
      k_mm16<<<dim3(8,16,2),256,0,stream>>>(ST1, ST2, (long long)1024*512,
                                            RHT1, RHT2, (long long)2048*512,
                                            Q1, Q2, 2048, (long long)1024*2048, inv256);
      // K4 (MFMA): candidates
      k_candm<<<dim3(64,1,2),256,0,stream>>>(P1, P2, Q1, Q2, Wc1a, Wc2a, Wc1b, Wc2b,
                                             bc, bc2, Cbuf);
      // K5: h update
      k_update<<<4096,256,0,stream>>>(Ubuf, Ubuf + (size_t)RRR*UU,
                                      Cbuf, Cbuf + (size_t)RRR*UU,
                                      h_l, xh_l, (l == 0) ? (XH + (size_t)RRR*CC) : nullptr);
    }
    if (!enc) {
      int p = step - TT;
      k_out<<<64,256,0,stream>>>(H + (size_t)RRR*UU, fow, fob, fiw, fib,
                                 (float*)d_out, XH, p);
    }
  }
}

// Round 5
// 5354.101 us; speedup vs baseline: 2.4939x; 1.2278x over previous
//
#include <hip/hip_runtime.h>
#include <math.h>

#define NN 512
#define BB 32
#define UU 64
#define CC 128
#define TT 12
#define NP 12
#define RRR (NN*BB)   // 16384 rows = (n,b)

typedef _Float16 f16;
typedef f16 f16x8 __attribute__((ext_vector_type(8)));
typedef f16 f16x4 __attribute__((ext_vector_type(4)));
typedef float f32x4 __attribute__((ext_vector_type(4)));

// direct global->LDS DMA, 16B per lane; dst wave-uniform base (lane*16 added by HW)
__device__ __forceinline__ void gload16(const f16* g, f16* l) {
  __builtin_amdgcn_global_load_lds((const __attribute__((address_space(1))) void*)g,
                                   (__attribute__((address_space(3))) void*)l, 16, 0, 0);
}

// ---- workspace layout (float units) ----
static const size_t OFF_ST    = 0;                              // [4][512][512] f32
static const size_t OFF_AH    = OFF_ST   + (size_t)4*512*512;
static const size_t OFF_INVD  = OFF_AH   + (size_t)2*512*512;
static const size_t OFF_XH    = OFF_INVD + 2048;                // [2][16384][128] f32
static const size_t OFF_H     = OFF_XH   + (size_t)2*RRR*CC;    // [2][16384][64] f32
static const size_t OFF_RH    = OFF_H    + (size_t)2*RRR*UU;    // [2][16384][64] f32
static const size_t OFF_U     = OFF_RH   + (size_t)2*RRR*UU;
static const size_t OFF_CB    = OFF_U    + (size_t)2*RRR*UU;
static const size_t OFF_F16   = OFF_CB   + (size_t)2*RRR*UU;
// f16 regions (float units = f16count/2)
static const size_t OFF_ST16A = OFF_F16;                        // 2048*512 f16
static const size_t OFF_ST16B = OFF_ST16A + 524288;
static const size_t OFF_XHT1  = OFF_ST16B + 524288;             // 4096*512 f16
static const size_t OFF_XHT2  = OFF_XHT1  + 1048576;
static const size_t OFF_RHT1  = OFF_XHT2  + 1048576;            // 2*2048*512 f16
static const size_t OFF_RHT2  = OFF_RHT1  + 1048576;
static const size_t OFF_P1    = OFF_RHT2  + 1048576;            // 2048*4096 f16
static const size_t OFF_P2    = OFF_P1    + 4194304;
static const size_t OFF_Q1    = OFF_P2    + 4194304;            // 4*512*2048 f16
static const size_t OFF_Q2    = OFF_Q1    + 2097152;
static const size_t OFF_WT1   = OFF_Q2    + 2097152;            // 393216 f16
static const size_t OFF_WT2   = OFF_WT1   + 196608;

// ---------- precompute ----------
__global__ void k_build_ah(const float* __restrict__ adj, const float* __restrict__ sm1,
                           const float* __restrict__ sm2, float* __restrict__ ah) {
  int a = blockIdx.y, i = blockIdx.x;
  const float* sm = a ? sm2 : sm1;
  for (int j = threadIdx.x; j < NN; j += blockDim.x) {
    float m = tanhf(0.5f * (sm[i*NN + j] + sm[j*NN + i])) + 1.0f;
    ah[((size_t)a*NN + i)*NN + j] = adj[i*NN + j] * m + ((i == j) ? 1.0f : 0.0f);
  }
}

__global__ void k_deg(const float* __restrict__ ah, float* __restrict__ invd) {
  int a = blockIdx.y, n = blockIdx.x;
  const float* A = ah + (size_t)a*NN*NN;
  __shared__ float sr[256], sc[256];
  int t = threadIdx.x;
  sr[t] = A[(size_t)n*NN + t] + A[(size_t)n*NN + t + 256];
  sc[t] = A[(size_t)t*NN + n] + A[(size_t)(t+256)*NN + n];
  __syncthreads();
  for (int s = 128; s > 0; s >>= 1) {
    if (t < s) { sr[t] += sr[t+s]; sc[t] += sc[t+s]; }
    __syncthreads();
  }
  if (t == 0) {
    float dr = sr[0], dc = sc[0];
    invd[(a*2 + 0)*NN + n] = dr > 0.f ? 1.f/dr : 0.f;
    invd[(a*2 + 1)*NN + n] = dc > 0.f ? 1.f/dc : 0.f;
  }
}

// ST[s][m][n]: s=2a+0: inv_dout[a][n]*ah[a][n][m] ; s=2a+1: inv_din[a][n]*ah[a][m][n]
__global__ void k_st(const float* __restrict__ ah, const float* __restrict__ invd,
                     float* __restrict__ ST) {
  int s = blockIdx.y, m = blockIdx.x;
  int a = s >> 1, dir = s & 1;
  const float* A = ah + (size_t)a*NN*NN;
  const float* inv = invd + (a*2 + dir)*NN;
  float* out = ST + ((size_t)s*NN + m)*NN;
  for (int n = threadIdx.x; n < NN; n += blockDim.x) {
    float v = dir ? A[(size_t)m*NN + n] : A[(size_t)n*NN + m];
    out[n] = inv[n] * v;
  }
}

// fp16 split of ST with x256 scale
__global__ void k_splitA(const float* __restrict__ s, f16* __restrict__ a1,
                         f16* __restrict__ a2, int total) {
  int i = blockIdx.x*blockDim.x + threadIdx.x;
  if (i >= total) return;
  float v = s[i] * 256.0f;
  f16 hi = (f16)v;
  a1[i] = hi;
  a2[i] = (f16)(v - (float)hi);
}

// weight transpose + sum + x256 split: w [2l][4][128][O] -> wt [2l][2fb][O][128]
__global__ void k_wsumt(const float* __restrict__ w, f16* __restrict__ wt1,
                        f16* __restrict__ wt2, int O) {
  int idx = blockIdx.x*blockDim.x + threadIdx.x;
  int total = 2*2*O*128;
  if (idx >= total) return;
  int i  = idx & 127;
  int o  = (idx >> 7) % O;
  int fb = (idx / (128*O)) & 1;
  int l  = idx / (128*O*2);
  const float* wl = w + (((size_t)(l*4 + fb*2)*128 + i)*O + o);
  float v = (wl[0] + wl[(size_t)128*O]) * 256.0f;
  f16 hi = (f16)v;
  size_t dst = ((size_t)(l*2 + fb)*O + o)*128 + i;
  wt1[dst] = hi;
  wt2[dst] = (f16)(v - (float)hi);
}

// transpose + fp16-split: src f32 [512 x lds_], dst f16 [cols x 512]
__launch_bounds__(256)
__global__ void k_tsplit(const float* __restrict__ src, int lds_, long long srcZ,
                         f16* __restrict__ d1, f16* __restrict__ d2, long long dstZ) {
  __shared__ float tile[64][65];
  const float* S = src + (size_t)blockIdx.z*srcZ;
  f16* D1 = d1 + (size_t)blockIdx.z*dstZ;
  f16* D2 = d2 + (size_t)blockIdx.z*dstZ;
  int t = threadIdx.x;
  int c0 = blockIdx.x*64, k0 = blockIdx.y*64;
#pragma unroll
  for (int it = 0; it < 4; ++it) {
    int r = (t >> 4) + it*16;
    int c = (t & 15)*4;
    float4 v = *(const float4*)(S + (size_t)(k0 + r)*lds_ + c0 + c);
    tile[r][c] = v.x; tile[r][c+1] = v.y; tile[r][c+2] = v.z; tile[r][c+3] = v.w;
  }
  __syncthreads();
#pragma unroll
  for (int it = 0; it < 4; ++it) {
    int c = (t >> 4) + it*16;       // dst row (source col)
    int ks = (t & 15)*4;
    f16x4 h1, h2;
#pragma unroll
    for (int j = 0; j < 4; ++j) {
      float v = tile[ks + j][c];
      f16 hi = (f16)v;
      h1[j] = hi;
      h2[j] = (f16)(v - (float)hi);
    }
    *(f16x4*)(D1 + (size_t)(c0 + c)*512 + k0 + ks) = h1;
    *(f16x4*)(D2 + (size_t)(c0 + c)*512 + k0 + ks) = h2;
  }
}

// ---------- fused fp16-split MFMA GEMM: C = (A1B1 + A1B2 + A2B1)*scale ----------
// Single staging of A1,A2,B1,B2 tiles per K-step; 3 products from LDS.
// MODE 0 (K1): 512 blocks = 16 row-tiles x 32 col-tiles, XCD c owns rows {2c,2c+1}.
// MODE 1 (K3): 256 blocks = 2 z x 8 x 16; XCD c: z=c>>2, rows {2(c&3),2(c&3)+1}.
template<int MODE>
__launch_bounds__(256)
__global__ void k_mm16f(const f16* __restrict__ A1g, const f16* __restrict__ A2g, long long aZ,
                        const f16* __restrict__ B1g, const f16* __restrict__ B2g, long long bZ,
                        f16* __restrict__ C1g, f16* __restrict__ C2g, int ldc, long long cZ,
                        float scale) {
  const int bid = blockIdx.x;
  const int c = bid & 7, i = bid >> 3;
  int x, y; long long z;
  if (MODE == 0) { x = 2*c + (i & 1); y = i >> 1; z = 0; }
  else           { z = c >> 2; x = 2*(c & 3) + (i & 1); y = i >> 1; }
  const f16* A1 = A1g + z*aZ; const f16* A2 = A2g + z*aZ;
  const f16* B1 = B1g + z*bZ; const f16* B2 = B2g + z*bZ;
  f16* C1 = C1g + z*cZ; f16* C2 = C2g + z*cZ;
  const int row0 = x*128, col0 = y*128;

  __shared__ __align__(16) f16 As1[128*64], As2[128*64], Bs1[128*64], Bs2[128*64];
  const int tid = threadIdx.x;
  const int lane = tid & 63, w = tid >> 6;
  const int wr = w >> 1, wc = w & 1;
  const int rq = lane >> 3;
  const int gq = ((lane & 7) ^ rq) * 8;

  f32x4 acc[4][4];
#pragma unroll
  for (int m = 0; m < 4; ++m)
#pragma unroll
    for (int n = 0; n < 4; ++n) acc[m][n] = (f32x4){0.f,0.f,0.f,0.f};

  for (int k0 = 0; k0 < 512; k0 += 64) {
    __syncthreads();
#pragma unroll
    for (int q = 0; q < 4; ++q) {
      const int rloc = w*32 + q*8;
      gload16(A1 + (size_t)(row0 + rloc + rq)*512 + k0 + gq, As1 + rloc*64);
      gload16(A2 + (size_t)(row0 + rloc + rq)*512 + k0 + gq, As2 + rloc*64);
      gload16(B1 + (size_t)(col0 + rloc + rq)*512 + k0 + gq, Bs1 + rloc*64);
      gload16(B2 + (size_t)(col0 + rloc + rq)*512 + k0 + gq, Bs2 + rloc*64);
    }
    __syncthreads();
#pragma unroll
    for (int ks = 0; ks < 2; ++ks) {
      const int gk = ks*4 + (lane >> 4);
      f16x8 a1f[4], a2f[4], b1f[4], b2f[4];
#pragma unroll
      for (int m = 0; m < 4; ++m) {
        const int ra = wr*64 + m*16 + (lane & 15);
        const int sa = ra*64 + ((gk ^ (ra & 7))*8);
        a1f[m] = *(const f16x8*)(As1 + sa);
        a2f[m] = *(const f16x8*)(As2 + sa);
        const int rb = wc*64 + m*16 + (lane & 15);
        const int sb = rb*64 + ((gk ^ (rb & 7))*8);
        b1f[m] = *(const f16x8*)(Bs1 + sb);
        b2f[m] = *(const f16x8*)(Bs2 + sb);
      }
#pragma unroll
      for (int m = 0; m < 4; ++m)
#pragma unroll
        for (int n = 0; n < 4; ++n) {
          acc[m][n] = __builtin_amdgcn_mfma_f32_16x16x32_f16(a1f[m], b1f[n], acc[m][n], 0, 0, 0);
          acc[m][n] = __builtin_amdgcn_mfma_f32_16x16x32_f16(a1f[m], b2f[n], acc[m][n], 0, 0, 0);
          acc[m][n] = __builtin_amdgcn_mfma_f32_16x16x32_f16(a2f[m], b1f[n], acc[m][n], 0, 0, 0);
        }
    }
  }
#pragma unroll
  for (int m = 0; m < 4; ++m) {
    const int row = row0 + wr*64 + m*16 + (lane >> 4)*4;
#pragma unroll
    for (int n = 0; n < 4; ++n) {
      const int col = col0 + wc*64 + n*16 + (lane & 15);
#pragma unroll
      for (int r = 0; r < 4; ++r) {
        float v = acc[m][n][r] * scale;
        f16 hi = (f16)v;
        C1[(size_t)(row + r)*ldc + col] = hi;
        C2[(size_t)(row + r)*ldc + col] = (f16)(v - (float)hi);
      }
    }
  }
}

// ---------- gates MFMA (fused passes): sigmoid epilogue ----------
__launch_bounds__(256)
__global__ void k_gatesmf(const f16* __restrict__ P1, const f16* __restrict__ P2,
                          const f16* __restrict__ W1g0, const f16* __restrict__ W2g0,
                          const f16* __restrict__ W1g1, const f16* __restrict__ W2g1,
                          const float* __restrict__ b0, const float* __restrict__ b1,
                          const float* __restrict__ h,
                          float* __restrict__ rh, float* __restrict__ ubuf) {
  const int g = blockIdx.z;
  const f16* W1 = g ? W1g1 : W1g0;
  const f16* W2 = g ? W2g1 : W2g0;
  const float* bias = g ? b1 : b0;
  float* rh_g = rh   + (size_t)g * RRR * UU;
  float* u_g  = ubuf + (size_t)g * RRR * UU;
  __shared__ __align__(16) f16 As1[128*64], As2[128*64], Bs1[128*64], Bs2[128*64];
  const int tid = threadIdx.x;
  const int lane = tid & 63, w = tid >> 6;
  const int wr = w >> 1, wc = w & 1;
  const int R0 = blockIdx.x * 128;
  const int rq = lane >> 3;
  const int gq = ((lane & 7) ^ rq) * 8;

  f32x4 acc[4][4];
#pragma unroll
  for (int m = 0; m < 4; ++m)
#pragma unroll
    for (int n = 0; n < 4; ++n) acc[m][n] = (f32x4){0.f,0.f,0.f,0.f};

  for (int sup = 0; sup < 2; ++sup) {
    const f16* A1 = P1 + (size_t)(2*g + sup)*RRR*CC;
    const f16* A2 = P2 + (size_t)(2*g + sup)*RRR*CC;
    const f16* B1 = W1 + (size_t)sup*16384;
    const f16* B2 = W2 + (size_t)sup*16384;
    for (int k0 = 0; k0 < 128; k0 += 64) {
      __syncthreads();
#pragma unroll
      for (int q = 0; q < 4; ++q) {
        const int rloc = w*32 + q*8;
        gload16(A1 + (size_t)(R0 + rloc + rq)*128 + k0 + gq, As1 + rloc*64);
        gload16(A2 + (size_t)(R0 + rloc + rq)*128 + k0 + gq, As2 + rloc*64);
        gload16(B1 + (size_t)(rloc + rq)*128 + k0 + gq, Bs1 + rloc*64);
        gload16(B2 + (size_t)(rloc + rq)*128 + k0 + gq, Bs2 + rloc*64);
      }
      __syncthreads();
#pragma unroll
      for (int ks = 0; ks < 2; ++ks) {
        const int gk = ks*4 + (lane >> 4);
        f16x8 a1f[4], a2f[4], b1f[4], b2f[4];
#pragma unroll
        for (int m = 0; m < 4; ++m) {
          const int ra = wr*64 + m*16 + (lane & 15);
          const int sa = ra*64 + ((gk ^ (ra & 7))*8);
          a1f[m] = *(const f16x8*)(As1 + sa);
          a2f[m] = *(const f16x8*)(As2 + sa);
          const int rb = wc*64 + m*16 + (lane & 15);
          const int sb = rb*64 + ((gk ^ (rb & 7))*8);
          b1f[m] = *(const f16x8*)(Bs1 + sb);
          b2f[m] = *(const f16x8*)(Bs2 + sb);
        }
#pragma unroll
        for (int m = 0; m < 4; ++m)
#pragma unroll
          for (int n = 0; n < 4; ++n) {
            acc[m][n] = __builtin_amdgcn_mfma_f32_16x16x32_f16(a1f[m], b1f[n], acc[m][n], 0, 0, 0);
            acc[m][n] = __builtin_amdgcn_mfma_f32_16x16x32_f16(a1f[m], b2f[n], acc[m][n], 0, 0, 0);
            acc[m][n] = __builtin_amdgcn_mfma_f32_16x16x32_f16(a2f[m], b1f[n], acc[m][n], 0, 0, 0);
          }
      }
    }
  }
#pragma unroll
  for (int m = 0; m < 4; ++m) {
    const int row = R0 + wr*64 + m*16 + (lane >> 4)*4;
#pragma unroll
    for (int n = 0; n < 4; ++n) {
      const int o = wc*64 + n*16 + (lane & 15);
#pragma unroll
      for (int r = 0; r < 4; ++r) {
        const int R = row + r;
        float v = acc[m][n][r] * 0.00390625f + bias[o];
        float sg = 1.f / (1.f + expf(-v));
        if (o < 64) rh_g[(size_t)R*UU + o] = sg * h[(size_t)R*UU + o];
        else        u_g[(size_t)R*UU + o - 64] = sg;
      }
    }
  }
}

// ---------- candidate MFMA (fused passes): tanh epilogue, 128-row tiles ----------
__launch_bounds__(256)
__global__ void k_candmf(const f16* __restrict__ P1, const f16* __restrict__ P2,
                         const f16* __restrict__ Q1, const f16* __restrict__ Q2,
                         const f16* __restrict__ Wc1g0, const f16* __restrict__ Wc2g0,
                         const f16* __restrict__ Wc1g1, const f16* __restrict__ Wc2g1,
                         const float* __restrict__ b0, const float* __restrict__ b1,
                         float* __restrict__ cbuf) {
  const int g = blockIdx.z;
  const f16* W1 = g ? Wc1g1 : Wc1g0;
  const f16* W2 = g ? Wc2g1 : Wc2g0;
  const float* bias = g ? b1 : b0;
  float* c_g = cbuf + (size_t)g * RRR * UU;
  __shared__ __align__(16) f16 As1[128*64], As2[128*64], Bs1[64*64], Bs2[64*64];
  const int tid = threadIdx.x;
  const int lane = tid & 63, w = tid >> 6;
  const int R0 = blockIdx.x * 128;
  const int rq = lane >> 3;
  const int gq = ((lane & 7) ^ rq) * 8;

  f32x4 acc[2][4];
#pragma unroll
  for (int m = 0; m < 2; ++m)
#pragma unroll
    for (int n = 0; n < 4; ++n) acc[m][n] = (f32x4){0.f,0.f,0.f,0.f};

  for (int seg = 0; seg < 4; ++seg) {
    const int sup = seg >> 1, isQ = seg & 1;
    const f16* A1 = isQ ? (Q1 + ((size_t)g*2 + sup)*1048576)
                        : (P1 + (size_t)(2*g + sup)*RRR*CC);
    const f16* A2 = isQ ? (Q2 + ((size_t)g*2 + sup)*1048576)
                        : (P2 + (size_t)(2*g + sup)*RRR*CC);
    const int lda = isQ ? 64 : 128;
    const f16* B1 = W1 + (size_t)sup*8192 + (isQ ? 64 : 0);
    const f16* B2 = W2 + (size_t)sup*8192 + (isQ ? 64 : 0);
    __syncthreads();
#pragma unroll
    for (int q = 0; q < 4; ++q) {
      const int rloc = w*32 + q*8;
      gload16(A1 + (size_t)(R0 + rloc + rq)*lda + gq, As1 + rloc*64);
      gload16(A2 + (size_t)(R0 + rloc + rq)*lda + gq, As2 + rloc*64);
    }
#pragma unroll
    for (int q = 0; q < 2; ++q) {
      const int rloc = w*16 + q*8;
      gload16(B1 + (size_t)(rloc + rq)*128 + gq, Bs1 + rloc*64);
      gload16(B2 + (size_t)(rloc + rq)*128 + gq, Bs2 + rloc*64);
    }
    __syncthreads();
#pragma unroll
    for (int ks = 0; ks < 2; ++ks) {
      const int gk = ks*4 + (lane >> 4);
      f16x8 a1f[2], a2f[2], b1f[4], b2f[4];
#pragma unroll
      for (int m = 0; m < 2; ++m) {
        const int ra = w*32 + m*16 + (lane & 15);
        const int sa = ra*64 + ((gk ^ (ra & 7))*8);
        a1f[m] = *(const f16x8*)(As1 + sa);
        a2f[m] = *(const f16x8*)(As2 + sa);
      }
#pragma unroll
      for (int n = 0; n < 4; ++n) {
        const int rb = n*16 + (lane & 15);
        const int sb = rb*64 + ((gk ^ (rb & 7))*8);
        b1f[n] = *(const f16x8*)(Bs1 + sb);
        b2f[n] = *(const f16x8*)(Bs2 + sb);
      }
#pragma unroll
      for (int m = 0; m < 2; ++m)
#pragma unroll
        for (int n = 0; n < 4; ++n) {
          acc[m][n] = __builtin_amdgcn_mfma_f32_16x16x32_f16(a1f[m], b1f[n], acc[m][n], 0, 0, 0);
          acc[m][n] = __builtin_amdgcn_mfma_f32_16x16x32_f16(a1f[m], b2f[n], acc[m][n], 0, 0, 0);
          acc[m][n] = __builtin_amdgcn_mfma_f32_16x16x32_f16(a2f[m], b1f[n], acc[m][n], 0, 0, 0);
        }
    }
  }
#pragma unroll
  for (int m = 0; m < 2; ++m) {
    const int row = R0 + w*32 + m*16 + (lane >> 4)*4;
#pragma unroll
    for (int n = 0; n < 4; ++n) {
      const int o = n*16 + (lane & 15);
#pragma unroll
      for (int r = 0; r < 4; ++r)
        c_g[(size_t)(row + r)*UU + o] = tanhf(acc[m][n][r] * 0.00390625f + bias[o]);
    }
  }
}

__global__ void k_xin(const float* __restrict__ x, const float* __restrict__ tm,
                      const float* __restrict__ fiw, const float* __restrict__ fib,
                      float* __restrict__ xh0, int t) {
  int idx = blockIdx.x*blockDim.x + threadIdx.x;  // 16384*64
  int u = idx & 63, R = idx >> 6;
  int b = R & 31, n = R >> 5;
  float xs = x[((size_t)b*TT + t)*NN + n] * (tanhf(tm[t*NN + n]) + 1.0f);
  xh0[(size_t)R*CC + u] = xs * fiw[u] + fib[u];
}

__global__ void k_decin0(const float* __restrict__ fib, float* __restrict__ xh0) {
  int idx = blockIdx.x*blockDim.x + threadIdx.x;
  int u = idx & 63, R = idx >> 6;
  xh0[(size_t)R*CC + u] = fib[u];   // go == 0
}

// ---------- GRU update ----------
__global__ void k_update(const float* __restrict__ u1, const float* __restrict__ u2,
                         const float* __restrict__ c1, const float* __restrict__ c2,
                         float* __restrict__ h, float* __restrict__ xh,
                         float* __restrict__ xh_next) {
  int idx = blockIdx.x*blockDim.x + threadIdx.x;  // 16384*64
  int R = idx >> 6, o = idx & 63;
  float u = 0.5f*(u1[idx] + u2[idx]);
  float c = 0.5f*(c1[idx] + c2[idx]);
  float hn = (1.f - u)*h[idx] + u*c;
  h[idx] = hn;
  xh[(size_t)R*CC + 64 + o] = hn;
  if (xh_next) xh_next[(size_t)R*CC + o] = hn;
}

// ---------- decoder output + next input ----------
__global__ void k_out(const float* __restrict__ h1, const float* __restrict__ fow,
                      const float* __restrict__ fob, const float* __restrict__ fiw,
                      const float* __restrict__ fib, float* __restrict__ out,
                      float* __restrict__ xh0, int p) {
  int R = blockIdx.x*blockDim.x + threadIdx.x;   // 16384
  int b = R & 31, n = R >> 5;
  const float* hr = h1 + (size_t)R*UU;
  float s = fob[0];
#pragma unroll
  for (int u = 0; u < UU; ++u) s = fmaf(hr[u], fow[u], s);
  out[(size_t)b*(NP*NN) + (size_t)p*NN + n] = s;
#pragma unroll
  for (int u = 0; u < UU; ++u) xh0[(size_t)R*CC + u] = fmaf(s, fiw[u], fib[u]);
}

extern "C" void kernel_launch(void* const* d_in, const int* in_sizes, int n_in,
                              void* d_out, int out_size, void* d_ws, size_t ws_size,
                              hipStream_t stream) {
  (void)in_sizes; (void)n_in; (void)out_size; (void)ws_size;
  const float* x   = (const float*)d_in[0];
  const float* adj = (const float*)d_in[1];
  const float* sm1 = (const float*)d_in[2];
  const float* sm2 = (const float*)d_in[3];
  const float* tm  = (const float*)d_in[4];
  const float* fiw = (const float*)d_in[5];
  const float* fib = (const float*)d_in[6];
  const float* fow = (const float*)d_in[7];
  const float* fob = (const float*)d_in[8];

  float* WS   = (float*)d_ws;
  float* ST   = WS + OFF_ST;
  float* AH   = WS + OFF_AH;
  float* INVD = WS + OFF_INVD;
  float* XH   = WS + OFF_XH;
  float* H    = WS + OFF_H;
  float* RH   = WS + OFF_RH;
  float* Ubuf = WS + OFF_U;
  float* Cbuf = WS + OFF_CB;
  f16* ST1  = (f16*)(WS + OFF_ST16A);
  f16* ST2  = (f16*)(WS + OFF_ST16B);
  f16* XHT1 = (f16*)(WS + OFF_XHT1);
  f16* XHT2 = (f16*)(WS + OFF_XHT2);
  f16* RHT1 = (f16*)(WS + OFF_RHT1);
  f16* RHT2 = (f16*)(WS + OFF_RHT2);
  f16* P1   = (f16*)(WS + OFF_P1);
  f16* P2   = (f16*)(WS + OFF_P2);
  f16* Q1   = (f16*)(WS + OFF_Q1);
  f16* Q2   = (f16*)(WS + OFF_Q2);
  f16* WT1  = (f16*)(WS + OFF_WT1);
  f16* WT2  = (f16*)(WS + OFF_WT2);

  // ---- supports ----
  k_build_ah<<<dim3(512,2),256,0,stream>>>(adj, sm1, sm2, AH);
  k_deg<<<dim3(512,2),256,0,stream>>>(AH, INVD);
  k_st<<<dim3(512,4),256,0,stream>>>(AH, INVD, ST);
  k_splitA<<<4096,256,0,stream>>>(ST, ST1, ST2, 2048*512);

  // ---- weight transposed split sums ----
  const int widx[8] = {9, 11, 13, 15, 17, 19, 21, 23};
  const int Osz[8]  = {128, 64, 128, 64, 128, 64, 128, 64};
  const size_t woff16[8] = {0, 65536, 98304, 163840, 196608, 262144, 294912, 360448};
  for (int tau = 0; tau < 8; ++tau) {
    int total = 2*2*Osz[tau]*128;
    k_wsumt<<<(total + 255)/256, 256, 0, stream>>>((const float*)d_in[widx[tau]],
                                                   WT1 + woff16[tau], WT2 + woff16[tau],
                                                   Osz[tau]);
  }

  hipMemsetAsync(XH, 0, (size_t)2*RRR*CC*sizeof(float), stream);
  hipMemsetAsync(H,  0, (size_t)2*RRR*UU*sizeof(float), stream);

  const float inv256 = 1.0f/256.0f;

  for (int step = 0; step < TT + NP; ++step) {
    const bool enc = step < TT;
    const int ph = enc ? 0 : 1;
    if (enc)             k_xin<<<4096,256,0,stream>>>(x, tm, fiw, fib, XH, step);
    else if (step == TT) k_decin0<<<4096,256,0,stream>>>(fib, XH);

    for (int l = 0; l < 2; ++l) {
      float* xh_l = XH + (size_t)l*RRR*CC;
      float* h_l  = H  + (size_t)l*RRR*UU;
      const size_t lru = (size_t)l*2*128*128;  // layer stride in WT for O=128
      const size_t lc  = (size_t)l*2*64*128;   // layer stride for O=64
      const f16* Wru1a = WT1 + woff16[ph*4+0] + lru;  // gate0 ru
      const f16* Wru2a = WT2 + woff16[ph*4+0] + lru;
      const f16* Wru1b = WT1 + woff16[ph*4+2] + lru;  // gate1 ru2
      const f16* Wru2b = WT2 + woff16[ph*4+2] + lru;
      const f16* Wc1a  = WT1 + woff16[ph*4+1] + lc;   // gate0 c
      const f16* Wc2a  = WT2 + woff16[ph*4+1] + lc;
      const f16* Wc1b  = WT1 + woff16[ph*4+3] + lc;   // gate1 c2
      const f16* Wc2b  = WT2 + woff16[ph*4+3] + lc;
      const float* bru  = (const float*)d_in[enc?10:18] + (size_t)l*128;
      const float* bc   = (const float*)d_in[enc?12:20] + (size_t)l*64;
      const float* bru2 = (const float*)d_in[enc?14:22] + (size_t)l*128;
      const float* bc2  = (const float*)d_in[enc?16:24] + (size_t)l*64;

      // transpose+split xh_l: [512 x 4096] -> XHT [4096 x 512] f16 hi/lo
      k_tsplit<<<dim3(64,8,1),256,0,stream>>>(xh_l, 4096, 0, XHT1, XHT2, 0);
      // K1 (fused MFMA): P[2048 x 4096] = ST@xh  (split f16 out)
      k_mm16f<0><<<512,256,0,stream>>>(ST1, ST2, 0, XHT1, XHT2, 0,
                                       P1, P2, 4096, 0, inv256);
      // K2 (fused MFMA): gates -> rh, u
      k_gatesmf<<<dim3(128,1,2),256,0,stream>>>(P1, P2, Wru1a, Wru2a, Wru1b, Wru2b,
                                                bru, bru2, h_l, RH, Ubuf);
      // transpose+split rh per gate: [512 x 2048] -> [2048 x 512]
      k_tsplit<<<dim3(32,8,2),256,0,stream>>>(RH, 2048, (long long)RRR*UU,
                                              RHT1, RHT2, (long long)2048*512);
      // K3 (fused MFMA): Q per gate: [1024 x 2048] = ST(pair g)@rh_g (split f16 out)
      k_mm16f<1><<<256,256,0,stream>>>(ST1, ST2, (long long)1024*512,
                                       RHT1, RHT2, (long long)2048*512,
                                       Q1, Q2, 2048, (long long)1024*2048, inv256);
      // K4 (fused MFMA): candidates
      k_candmf<<<dim3(128,1,2),256,0,stream>>>(P1, P2, Q1, Q2, Wc1a, Wc2a, Wc1b, Wc2b,
                                               bc, bc2, Cbuf);
      // K5: h update
      k_update<<<4096,256,0,stream>>>(Ubuf, Ubuf + (size_t)RRR*UU,
                                      Cbuf, Cbuf + (size_t)RRR*UU,
                                      h_l, xh_l, (l == 0) ? (XH + (size_t)RRR*CC) : nullptr);
    }
    if (!enc) {
      int p = step - TT;
      k_out<<<64,256,0,stream>>>(H + (size_t)RRR*UU, fow, fob, fiw, fib,
                                 (float*)d_out, XH, p);
    }
  }
}